// Round 1
// baseline (3633.802 us; speedup 1.0000x reference)
//
#include <hip/hip_runtime.h>
#include <math.h>

#define DD 512
#define NN 4096
#define NS 258
#define RHO_ 100.0
#define SIG_ 1e-3
#define ALPHA_ 200.0
#define NITER 150
#define DELTA0 (3969.0 + SIG_ + RHO_)

// ---------------- workspace byte offsets ----------------
#define OFF_MP0    0u         // double[64*64]
#define OFF_NFT    32768u     // double[64]
#define OFF_NFD    33280u     // double[64]
#define OFF_U1     33792u     // float[64*512]
#define OFF_U2     164864u    // float[64*512]
#define OFF_E1     295936u    // double[64*512]
#define OFF_E2     558080u    // double[64*512]
#define OFF_P      820224u    // double[4096]
#define OFF_W      852992u    // double[4096]
#define OFF_SUMS   885760u    // double[392]: [0..2]=S_m, [8+m*64+b]=cs_m, [200+m*64+a]=rs_m
#define OFF_KS     889856u    // double[258*258]
#define OFF_TEMP   1422368u   // double[64*258]
#define OFF_COLBUF 1554464u   // double[258*64]
#define OFF_PINV   1686560u   // double[64*64]
#define OFF_NCM    1719328u   // double[258*258] (transposed N for coalesced matvec)
#define OFF_X      2251840u   // float[4096]

__device__ __forceinline__ double wsum64(double v){
  for (int m = 32; m >= 1; m >>= 1) v += __shfl_xor(v, m, 64);
  return v;
}
__device__ __forceinline__ double wmax64(double v){
  for (int m = 32; m >= 1; m >>= 1) v = fmax(v, __shfl_xor(v, m, 64));
  return v;
}

// ---- K1: row norms of feat_tra/feat_det + Mp0 = ft @ fd^T + iou ----
__global__ void k_mp0(const float* ft, const float* fd, const float* iou,
                      double* Mp0, double* nft, double* nfd){
  __shared__ float row[DD];
  __shared__ double red[256];
  int i = blockIdx.x, tid = threadIdx.x;
  for (int k = tid; k < DD; k += 256) row[k] = ft[i*DD + k];
  __syncthreads();
  double s = 0, s2 = 0;
  for (int k = tid; k < DD; k += 256){
    double a = row[k]; s += a*a;
    double bq = fd[i*DD + k]; s2 += bq*bq;
  }
  red[tid] = s; __syncthreads();
  for (int o = 128; o; o >>= 1){ if (tid < o) red[tid] += red[tid+o]; __syncthreads(); }
  if (tid == 0) nft[i] = red[0];
  __syncthreads();
  red[tid] = s2; __syncthreads();
  for (int o = 128; o; o >>= 1){ if (tid < o) red[tid] += red[tid+o]; __syncthreads(); }
  if (tid == 0) nfd[i] = red[0];
  __syncthreads();
  int j = tid >> 2, sub = tid & 3;
  double acc = 0;
  for (int k = sub*128; k < sub*128 + 128; ++k)
    acc += (double)row[k] * (double)fd[j*DD + k];
  red[tid] = acc; __syncthreads();
  if (sub == 0)
    Mp0[i*64 + j] = red[tid] + red[tid+1] + red[tid+2] + red[tid+3] + (double)iou[i*64 + j];
}

// ---- K2/K3: m1/m2 + lambda scaling -> u rows (fp32) ----
__global__ void k_ubuild(const float* ft, const float* fd, const double* Mp0,
                         const double* nrm_self, float* uo, int which){
  __shared__ double mrow[64];
  __shared__ double red[256];
  __shared__ double lam_s;
  int i = blockIdx.x, tid = threadIdx.x;
  if (tid < 64) mrow[tid] = (which == 1) ? Mp0[i*64 + tid] : Mp0[tid*64 + i];
  __syncthreads();
  const float* base = (which == 1) ? fd : ft;   // matrix multiplied by Mp0 row/col
  const float* self = (which == 1) ? ft : fd;
  double mv[2]; double nm = 0;
  for (int h = 0; h < 2; ++h){
    int c = tid + h*256;
    double acc = 0;
    for (int a = 0; a < 64; ++a) acc += mrow[a] * (double)base[a*DD + c];
    mv[h] = acc; nm += acc*acc;
  }
  red[tid] = nm; __syncthreads();
  for (int o = 128; o; o >>= 1){ if (tid < o) red[tid] += red[tid+o]; __syncthreads(); }
  if (tid == 0) lam_s = sqrt(nrm_self[i] / red[0]);
  __syncthreads();
  double lam = lam_s;
  for (int h = 0; h < 2; ++h){
    int c = tid + h*256;
    uo[i*DD + c] = (float)((double)self[i*DD + c] + lam * mv[h]);
  }
}

// ---- K4: e = l2norm(relu(u @ W^T + b)), stored fp64 ----
__global__ void k_egemm(const float* u1, const float* u2, const float* Wm, const float* bb,
                        double* e1, double* e2){
  __shared__ float urow[DD];
  __shared__ double red[256];
  __shared__ double nrm_s;
  int r = blockIdx.x, tid = threadIdx.x;
  const float* u = (r < 64) ? (u1 + r*DD) : (u2 + (size_t)(r-64)*DD);
  double* e = (r < 64) ? (e1 + r*DD) : (e2 + (size_t)(r-64)*DD);
  for (int k = tid; k < DD; k += 256) urow[k] = u[k];
  __syncthreads();
  double v[2]; double nm = 0;
  for (int h = 0; h < 2; ++h){
    int c = tid + h*256;
    const float* wr = Wm + (size_t)c*DD;
    double acc = (double)bb[c];
    for (int k = 0; k < DD; k += 4){
      float4 wq = *(const float4*)(wr + k);
      acc += (double)urow[k]   * (double)wq.x + (double)urow[k+1] * (double)wq.y
           + (double)urow[k+2] * (double)wq.z + (double)urow[k+3] * (double)wq.w;
    }
    acc = fmax(acc, 0.0);
    v[h] = acc; nm += acc*acc;
  }
  red[tid] = nm; __syncthreads();
  for (int o = 128; o; o >>= 1){ if (tid < o) red[tid] += red[tid+o]; __syncthreads(); }
  if (tid == 0) nrm_s = fmax(sqrt(red[0]), 1e-12);
  __syncthreads();
  double inv = 1.0 / nrm_s;
  for (int h = 0; h < 2; ++h) e[tid + h*256] = v[h] * inv;
}

// ---- K5: p[a*64+b] = e1[b].e2[a]; w = 1/(DELTA0 - p) ----
__global__ void k_pw(const double* e1, const double* e2, double* p, double* w){
  __shared__ double erow[DD];
  __shared__ double red[256];
  int a = blockIdx.x, tid = threadIdx.x;
  for (int k = tid; k < DD; k += 256) erow[k] = e2[a*DD + k];
  __syncthreads();
  int b = tid >> 2, sub = tid & 3;
  double acc = 0;
  for (int k = sub*128; k < sub*128 + 128; ++k) acc += e1[b*DD + k] * erow[k];
  red[tid] = acc; __syncthreads();
  if (sub == 0){
    double pv = red[tid] + red[tid+1] + red[tid+2] + red[tid+3];
    p[a*64 + b] = pv;
    w[a*64 + b] = 1.0 / (DELTA0 - pv);
  }
}

// ---- K5b: totals / col-sums / row-sums of w, w*p, w*p^2 ----
__global__ void k_sums(const double* p, const double* w, double* sums){
  __shared__ double red[256*3];
  int tid = threadIdx.x;
  int a = tid >> 2, sub = tid & 3;
  double r0 = 0, r1 = 0, r2 = 0;
  for (int b = sub*16; b < sub*16 + 16; ++b){
    double wv = w[a*64 + b], pv = p[a*64 + b];
    r0 += wv; r1 += wv*pv; r2 += wv*pv*pv;
  }
  red[tid*3] = r0; red[tid*3+1] = r1; red[tid*3+2] = r2;
  __syncthreads();
  if (tid < 64){
    double t0 = 0, t1 = 0, t2 = 0;
    for (int s = 0; s < 4; ++s){
      t0 += red[(tid*4+s)*3]; t1 += red[(tid*4+s)*3+1]; t2 += red[(tid*4+s)*3+2];
    }
    sums[200 + tid] = t0; sums[200 + 64 + tid] = t1; sums[200 + 128 + tid] = t2; // rs_m[a]
  }
  __syncthreads();
  int b2 = tid >> 2;
  double c0 = 0, c1 = 0, c2 = 0;
  for (int a2 = sub*16; a2 < sub*16 + 16; ++a2){
    double wv = w[a2*64 + b2], pv = p[a2*64 + b2];
    c0 += wv; c1 += wv*pv; c2 += wv*pv*pv;
  }
  __syncthreads();
  red[tid*3] = c0; red[tid*3+1] = c1; red[tid*3+2] = c2;
  __syncthreads();
  if (tid < 64){
    double t0 = 0, t1 = 0, t2 = 0;
    for (int s = 0; s < 4; ++s){
      t0 += red[(tid*4+s)*3]; t1 += red[(tid*4+s)*3+1]; t2 += red[(tid*4+s)*3+2];
    }
    sums[8 + tid] = t0; sums[8 + 64 + tid] = t1; sums[8 + 128 + tid] = t2; // cs_m[b]
  }
  __syncthreads();
  if (tid == 0){
    double t0 = 0, t1 = 0, t2 = 0;
    for (int a3 = 0; a3 < 64; ++a3){
      t0 += sums[200 + a3]; t1 += sums[200 + 64 + a3]; t2 += sums[200 + 128 + a3];
    }
    sums[0] = t0; sums[1] = t1; sums[2] = t2;
  }
}

// ---- K6: assemble Ksmall = M^-1 + B^T diag(w) B in order [E',F',g',g,E,F] ----
__device__ __forceinline__ void decode_idx(int t, int& cls, int& pr, int& ix){
  if (t < 64)       { cls = 1; pr = 1; ix = t; }
  else if (t < 128) { cls = 2; pr = 1; ix = t - 64; }
  else if (t == 128){ cls = 0; pr = 1; ix = 0; }
  else if (t == 129){ cls = 0; pr = 0; ix = 0; }
  else if (t < 194) { cls = 1; pr = 0; ix = t - 130; }
  else              { cls = 2; pr = 0; ix = t - 194; }
}

__global__ void k_ksmall(const double* p, const double* w, const double* sums, double* Ks){
  int idx = blockIdx.x*256 + threadIdx.x;
  if (idx >= NS*NS) return;
  int r = idx / NS, c = idx % NS;
  int cr, prr, ir, cc, prc, ic;
  decode_idx(r, cr, prr, ir);
  decode_idx(c, cc, prc, ic);
  int m = prr + prc;
  double tval;
  if (cr == 0 && cc == 0)      tval = sums[m];
  else if (cr == 0 && cc == 1) tval = sums[8 + m*64 + ic];
  else if (cr == 1 && cc == 0) tval = sums[8 + m*64 + ir];
  else if (cr == 0 && cc == 2) tval = sums[200 + m*64 + ic];
  else if (cr == 2 && cc == 0) tval = sums[200 + m*64 + ir];
  else if (cr == 1 && cc == 1) tval = (ir == ic) ? sums[8 + m*64 + ir] : 0.0;
  else if (cr == 2 && cc == 2) tval = (ir == ic) ? sums[200 + m*64 + ir] : 0.0;
  else if (cr == 1 && cc == 2){ // (E_i, F_j) -> val(a=ic, b=ir)
    double wv = w[ic*64 + ir], pv = p[ic*64 + ir];
    tval = (m == 0) ? wv : (m == 1) ? wv*pv : wv*pv*pv;
  } else {                      // (F_i, E_j) -> val(a=ir, b=ic)
    double wv = w[ir*64 + ic], pv = p[ir*64 + ic];
    tval = (m == 0) ? wv : (m == 1) ? wv*pv : wv*pv*pv;
  }
  double mv = 0.0;
  if (cr == 0 && cc == 0 && prr != prc) mv = -2.0;           // g <-> g'
  if (cr != 0 && cr == cc && ir == ic){
    if (prr != prc) mv = 2.0;                                 // E<->E', F<->F'
    else if (prr == 1) mv = -4.0 * RHO_;                      // E'E', F'F' diag
  }
  Ks[idx] = tval + mv;
}

// ---- block Gauss-Jordan inversion kernels ----
__global__ void k_pivinv(const double* Ks, double* Pinv, int start, int m){
  __shared__ double M[64][65];
  __shared__ double pk_s;
  int tid = threadIdx.x;
  for (int idx = tid; idx < m*m; idx += 256){
    int i = idx / m, j = idx % m;
    M[i][j] = Ks[(start+i)*NS + start + j];
  }
  __syncthreads();
  for (int k = 0; k < m; ++k){
    if (tid == 0) pk_s = 1.0 / M[k][k];
    __syncthreads();
    double pk = pk_s;
    if (tid < m && tid != k) M[k][tid] *= pk;
    __syncthreads();
    for (int idx = tid; idx < m*m; idx += 256){
      int i = idx / m, j = idx % m;
      if (i != k && j != k) M[i][j] -= M[i][k] * M[k][j];
    }
    __syncthreads();
    if (tid < m){
      if (tid != k) M[tid][k] = -M[tid][k] * pk;
      else M[k][k] = pk;
    }
    __syncthreads();
  }
  for (int idx = tid; idx < m*m; idx += 256){
    int i = idx / m, j = idx % m;
    Pinv[i*64 + j] = M[i][j];
  }
}

__global__ void k_pivrow(const double* Ks, const double* Pinv, double* temp, int start, int m){
  int idx = blockIdx.x*256 + threadIdx.x;
  if (idx >= m*NS) return;
  int r = idx / NS, c = idx % NS;
  if (c >= start && c < start + m){
    temp[r*NS + c] = Pinv[r*64 + (c - start)];
  } else {
    double acc = 0;
    for (int k = 0; k < m; ++k) acc += Pinv[r*64 + k] * Ks[(start+k)*NS + c];
    temp[r*NS + c] = acc;
  }
}

__global__ void k_trail(double* Ks, const double* temp, int start, int m){
  int idx = blockIdx.x*256 + threadIdx.x;
  if (idx >= NS*NS) return;
  int r = idx / NS, c = idx % NS;
  if (r >= start && r < start + m) return;
  if (c >= start && c < start + m) return;
  double acc = 0;
  for (int k = 0; k < m; ++k) acc += Ks[r*NS + start + k] * temp[k*NS + c];
  Ks[r*NS + c] -= acc;
}

__global__ void k_col(const double* Ks, const double* Pinv, double* colbuf, int start, int m){
  int idx = blockIdx.x*256 + threadIdx.x;
  if (idx >= NS*m) return;
  int r = idx / m, kp = idx % m;
  if (r >= start && r < start + m) return;
  double acc = 0;
  for (int k = 0; k < m; ++k) acc += Ks[r*NS + start + k] * Pinv[k*64 + kp];
  colbuf[r*64 + kp] = -acc;
}

__global__ void k_copyback(double* Ks, const double* temp, const double* colbuf, int start, int m){
  int idx = blockIdx.x*256 + threadIdx.x;
  if (idx < m*NS){
    int r = idx / NS, c = idx % NS;
    Ks[(start+r)*NS + c] = temp[r*NS + c];
  }
  int idx2 = idx - m*NS;
  if (idx2 >= 0 && idx2 < NS*m){
    int r = idx2 / m, kp = idx2 % m;
    if (!(r >= start && r < start + m)) Ks[r*NS + start + kp] = colbuf[r*64 + kp];
  }
}

// ---- transpose N for coalesced matvec ----
__global__ void k_ntrans(const double* Ks, double* Ncm){
  int idx = blockIdx.x*256 + threadIdx.x;
  if (idx >= NS*NS) return;
  int i = idx / NS, j = idx % NS;
  Ncm[j*NS + i] = Ks[i*NS + j];
}

// ---- K9: persistent single-workgroup ADMM (150 iterations) ----
__global__ __launch_bounds__(1024) void k_admm(const double* __restrict__ p,
                                               const double* __restrict__ w,
                                               const double* __restrict__ Ncm,
                                               float* __restrict__ x){
  __shared__ double v[NN];
  __shared__ double cspA[16][64];
  __shared__ double cspB[16][64];
  __shared__ double s1[NS];
  __shared__ double s2[NS];
  __shared__ double y2a[64], y2b[64];
  __shared__ double rsx_s[64];
  int tid = threadIdx.x;
  int lane = tid & 63;
  int wvid = tid >> 6;
  for (int j = tid; j < NN; j += 1024){ v[j] = 0.0; x[j] = 0.0f; }
  if (tid < 64){ y2a[tid] = 0.0; y2b[tid] = 0.0; }
  __syncthreads();
  int b = lane;
  for (int it = 0; it < NITER; ++it){
    // stage 1: rhs -> t, p*t; reductions for s1
    double cl_t = 0.0, cl_pt = 0.0;
    for (int q = 0; q < 4; ++q){
      int a = wvid*4 + q;
      int j = a*64 + b;
      double rhs = SIG_ * (double)x[j] + p[j] + RHO_ * fabs(v[j])
                 + (RHO_ - y2b[b]) + (RHO_ - y2a[a]);
      double t  = w[j] * rhs;
      double pt = p[j] * t;
      cl_t += t; cl_pt += pt;
      double rt  = wsum64(t);
      double rpt = wsum64(pt);
      if (lane == 0){ s1[194 + a] = rt; s1[64 + a] = rpt; }
    }
    cspA[wvid][lane] = cl_t;
    cspB[wvid][lane] = cl_pt;
    __syncthreads();
    // stage 2a: col sums
    if (tid < 64){
      double sum = 0;
      for (int ww = 0; ww < 16; ++ww) sum += cspA[ww][tid];
      s1[130 + tid] = sum;
    } else if (tid < 128){
      int bb = tid - 64;
      double sum = 0;
      for (int ww = 0; ww < 16; ++ww) sum += cspB[ww][bb];
      s1[bb] = sum;
    }
    __syncthreads();
    // stage 2b: totals
    if (tid < 64){
      double sv = wsum64(s1[130 + tid]);
      if (tid == 0) s1[129] = sv;
    } else if (tid < 128){
      double sv = wsum64(s1[tid - 64]);
      if (tid == 64) s1[128] = sv;
    }
    __syncthreads();
    // stage 3: s2 = N * s1 (coalesced via transposed N)
    if (tid < NS){
      double acc = 0;
      for (int jj = 0; jj < NS; ++jj) acc += Ncm[jj*NS + tid] * s1[jj];
      s2[tid] = acc;
    }
    __syncthreads();
    // stage 4: x update + v (z/y) update + sums of x
    double alpha = s2[129], alphap = s2[128];
    double cl_x = 0.0;
    for (int q = 0; q < 4; ++q){
      int a = wvid*4 + q;
      int j = a*64 + b;
      double pv = p[j], wvv = w[j];
      double rhs = SIG_ * (double)x[j] + pv + RHO_ * fabs(v[j])
                 + (RHO_ - y2b[b]) + (RHO_ - y2a[a]);
      double t = wvv * rhs;
      double corr = alpha + s2[130 + b] + s2[194 + a]
                  + pv * (alphap + s2[b] + s2[64 + a]);
      double xn = t - wvv * corr;
      double vo = v[j];
      v[j] = xn + fmin(vo, 0.0);
      x[j] = (float)xn;
      cl_x += xn;
      double rx = wsum64(xn);
      if (lane == 0) rsx_s[a] = rx;
    }
    cspA[wvid][lane] = cl_x;
    __syncthreads();
    // stage 5: dual updates for sum constraints
    if (tid < 64){
      double sum = 0;
      for (int ww = 0; ww < 16; ++ww) sum += cspA[ww][tid];
      y2b[tid] += RHO_ * (sum - 1.0);
    } else if (tid < 128){
      int aa = tid - 64;
      y2a[aa] += RHO_ * (rsx_s[aa] - 1.0);
    }
    __syncthreads();
  }
}

// ---- K10: clip + softmax(alpha*s, axis=-1) ----
__global__ __launch_bounds__(1024) void k_softmax(const float* __restrict__ x,
                                                  float* __restrict__ out){
  int tid = threadIdx.x;
  int lane = tid & 63, wvid = tid >> 6;
  for (int q = 0; q < 4; ++q){
    int i = wvid*4 + q;                  // output row (n1 index)
    double val = (double)x[lane*64 + i]; // s[i,j] = x[j*64+i]
    val = fmin(fmax(val, 0.0), 1.0);
    double mx = wmax64(val);
    double e = exp(ALPHA_ * (val - mx));
    double sm = wsum64(e);
    out[i*64 + lane] = (float)(e / sm);
  }
}

extern "C" void kernel_launch(void* const* d_in, const int* in_sizes, int n_in,
                              void* d_out, int out_size, void* d_ws, size_t ws_size,
                              hipStream_t stream){
  (void)in_sizes; (void)n_in; (void)out_size; (void)ws_size;
  const float* ft  = (const float*)d_in[0];
  const float* fd  = (const float*)d_in[1];
  const float* iou = (const float*)d_in[2];
  const float* Wm  = (const float*)d_in[3];
  const float* bb  = (const float*)d_in[4];
  char* ws = (char*)d_ws;
  double* Mp0    = (double*)(ws + OFF_MP0);
  double* nft    = (double*)(ws + OFF_NFT);
  double* nfd    = (double*)(ws + OFF_NFD);
  float*  u1     = (float*) (ws + OFF_U1);
  float*  u2     = (float*) (ws + OFF_U2);
  double* e1     = (double*)(ws + OFF_E1);
  double* e2     = (double*)(ws + OFF_E2);
  double* p      = (double*)(ws + OFF_P);
  double* w      = (double*)(ws + OFF_W);
  double* sums   = (double*)(ws + OFF_SUMS);
  double* Ks     = (double*)(ws + OFF_KS);
  double* temp   = (double*)(ws + OFF_TEMP);
  double* colbuf = (double*)(ws + OFF_COLBUF);
  double* Pinv   = (double*)(ws + OFF_PINV);
  double* Ncm    = (double*)(ws + OFF_NCM);
  float*  x      = (float*) (ws + OFF_X);

  hipLaunchKernelGGL(k_mp0,    dim3(64),  dim3(256), 0, stream, ft, fd, iou, Mp0, nft, nfd);
  hipLaunchKernelGGL(k_ubuild, dim3(64),  dim3(256), 0, stream, ft, fd, Mp0, nft, u1, 1);
  hipLaunchKernelGGL(k_ubuild, dim3(64),  dim3(256), 0, stream, ft, fd, Mp0, nfd, u2, 2);
  hipLaunchKernelGGL(k_egemm,  dim3(128), dim3(256), 0, stream, u1, u2, Wm, bb, e1, e2);
  hipLaunchKernelGGL(k_pw,     dim3(64),  dim3(256), 0, stream, e1, e2, p, w);
  hipLaunchKernelGGL(k_sums,   dim3(1),   dim3(256), 0, stream, p, w, sums);
  hipLaunchKernelGGL(k_ksmall, dim3((NS*NS+255)/256), dim3(256), 0, stream, p, w, sums, Ks);

  const int starts[5] = {0, 64, 128, 130, 194};
  const int msz[5]    = {64, 64, 2, 64, 64};
  for (int pv = 0; pv < 5; ++pv){
    int s0 = starts[pv], m = msz[pv];
    hipLaunchKernelGGL(k_pivinv,   dim3(1),                   dim3(256), 0, stream, Ks, Pinv, s0, m);
    hipLaunchKernelGGL(k_pivrow,   dim3((m*NS+255)/256),      dim3(256), 0, stream, Ks, Pinv, temp, s0, m);
    hipLaunchKernelGGL(k_trail,    dim3((NS*NS+255)/256),     dim3(256), 0, stream, Ks, temp, s0, m);
    hipLaunchKernelGGL(k_col,      dim3((NS*m+255)/256),      dim3(256), 0, stream, Ks, Pinv, colbuf, s0, m);
    hipLaunchKernelGGL(k_copyback, dim3((2*m*NS+255)/256),    dim3(256), 0, stream, Ks, temp, colbuf, s0, m);
  }
  hipLaunchKernelGGL(k_ntrans,  dim3((NS*NS+255)/256), dim3(256), 0, stream, Ks, Ncm);
  hipLaunchKernelGGL(k_admm,    dim3(1), dim3(1024), 0, stream, p, w, Ncm, x);
  hipLaunchKernelGGL(k_softmax, dim3(1), dim3(1024), 0, stream, x, (float*)d_out);
}

// Round 2
// 3513.063 us; speedup vs baseline: 1.0344x; 1.0344x over previous
//
#include <hip/hip_runtime.h>
#include <math.h>

#define DD 512
#define NN 4096
#define NS 258
#define RHO_ 100.0
#define SIG_ 1e-3
#define ALPHA_ 200.0
#define NITER 150
#define DELTA0 (3969.0 + SIG_ + RHO_)

// ---------------- workspace byte offsets ----------------
#define OFF_MP0    0u         // double[64*64]
#define OFF_NFT    32768u     // double[64]
#define OFF_NFD    33280u     // double[64]
#define OFF_U1     33792u     // float[64*512]
#define OFF_U2     164864u    // float[64*512]
#define OFF_E1     295936u    // double[64*512]
#define OFF_E2     558080u    // double[64*512]
#define OFF_P      820224u    // double[4096]
#define OFF_W      852992u    // double[4096]
#define OFF_SUMS   885760u    // double[392]
#define OFF_KS     889856u    // double[258*258]
#define OFF_TEMP   1422368u   // double[64*258]
#define OFF_COLBUF 1554464u   // double[258*64]
#define OFF_PINV   1686560u   // double[64*64]
#define OFF_N32    1719328u   // float[258*258]

__device__ __forceinline__ double wsum64(double v){
  for (int m = 32; m >= 1; m >>= 1) v += __shfl_xor(v, m, 64);
  return v;
}
__device__ __forceinline__ double wmax64(double v){
  for (int m = 32; m >= 1; m >>= 1) v = fmax(v, __shfl_xor(v, m, 64));
  return v;
}

// ---- K1: row norms of feat_tra/feat_det + Mp0 = ft @ fd^T + iou ----
__global__ void k_mp0(const float* ft, const float* fd, const float* iou,
                      double* Mp0, double* nft, double* nfd){
  __shared__ float row[DD];
  __shared__ double red[256];
  int i = blockIdx.x, tid = threadIdx.x;
  for (int k = tid; k < DD; k += 256) row[k] = ft[i*DD + k];
  __syncthreads();
  double s = 0, s2 = 0;
  for (int k = tid; k < DD; k += 256){
    double a = row[k]; s += a*a;
    double bq = fd[i*DD + k]; s2 += bq*bq;
  }
  red[tid] = s; __syncthreads();
  for (int o = 128; o; o >>= 1){ if (tid < o) red[tid] += red[tid+o]; __syncthreads(); }
  if (tid == 0) nft[i] = red[0];
  __syncthreads();
  red[tid] = s2; __syncthreads();
  for (int o = 128; o; o >>= 1){ if (tid < o) red[tid] += red[tid+o]; __syncthreads(); }
  if (tid == 0) nfd[i] = red[0];
  __syncthreads();
  int j = tid >> 2, sub = tid & 3;
  double acc = 0;
  for (int k = sub*128; k < sub*128 + 128; ++k)
    acc += (double)row[k] * (double)fd[j*DD + k];
  red[tid] = acc; __syncthreads();
  if (sub == 0)
    Mp0[i*64 + j] = red[tid] + red[tid+1] + red[tid+2] + red[tid+3] + (double)iou[i*64 + j];
}

// ---- K2: fused m1/m2 + lambda scaling -> u rows (fp32), 128 blocks ----
__global__ void k_ubuild2(const float* ft, const float* fd, const double* Mp0,
                          const double* nft, const double* nfd, float* u1, float* u2){
  __shared__ double mrow[64];
  __shared__ double red[256];
  __shared__ double lam_s;
  int blk = blockIdx.x, tid = threadIdx.x;
  int which = (blk < 64) ? 1 : 2;
  int i = blk & 63;
  if (tid < 64) mrow[tid] = (which == 1) ? Mp0[i*64 + tid] : Mp0[tid*64 + i];
  __syncthreads();
  const float* base = (which == 1) ? fd : ft;
  const float* self = (which == 1) ? ft : fd;
  const double* nrm_self = (which == 1) ? nft : nfd;
  float* uo = (which == 1) ? u1 : u2;
  double mv[2]; double nm = 0;
  for (int h = 0; h < 2; ++h){
    int c = tid + h*256;
    double acc = 0;
    for (int a = 0; a < 64; ++a) acc += mrow[a] * (double)base[a*DD + c];
    mv[h] = acc; nm += acc*acc;
  }
  red[tid] = nm; __syncthreads();
  for (int o = 128; o; o >>= 1){ if (tid < o) red[tid] += red[tid+o]; __syncthreads(); }
  if (tid == 0) lam_s = sqrt(nrm_self[i] / red[0]);
  __syncthreads();
  double lam = lam_s;
  for (int h = 0; h < 2; ++h){
    int c = tid + h*256;
    uo[i*DD + c] = (float)((double)self[i*DD + c] + lam * mv[h]);
  }
}

// ---- K3: e = l2norm(relu(u @ W^T + b)), stored fp64 ----
__global__ void k_egemm(const float* u1, const float* u2, const float* Wm, const float* bb,
                        double* e1, double* e2){
  __shared__ float urow[DD];
  __shared__ double red[256];
  __shared__ double nrm_s;
  int r = blockIdx.x, tid = threadIdx.x;
  const float* u = (r < 64) ? (u1 + r*DD) : (u2 + (size_t)(r-64)*DD);
  double* e = (r < 64) ? (e1 + r*DD) : (e2 + (size_t)(r-64)*DD);
  for (int k = tid; k < DD; k += 256) urow[k] = u[k];
  __syncthreads();
  double v[2]; double nm = 0;
  for (int h = 0; h < 2; ++h){
    int c = tid + h*256;
    const float* wr = Wm + (size_t)c*DD;
    double acc = (double)bb[c];
    for (int k = 0; k < DD; k += 4){
      float4 wq = *(const float4*)(wr + k);
      acc += (double)urow[k]   * (double)wq.x + (double)urow[k+1] * (double)wq.y
           + (double)urow[k+2] * (double)wq.z + (double)urow[k+3] * (double)wq.w;
    }
    acc = fmax(acc, 0.0);
    v[h] = acc; nm += acc*acc;
  }
  red[tid] = nm; __syncthreads();
  for (int o = 128; o; o >>= 1){ if (tid < o) red[tid] += red[tid+o]; __syncthreads(); }
  if (tid == 0) nrm_s = fmax(sqrt(red[0]), 1e-12);
  __syncthreads();
  double inv = 1.0 / nrm_s;
  for (int h = 0; h < 2; ++h) e[tid + h*256] = v[h] * inv;
}

// ---- K4: p[a*64+b] = e1[b].e2[a]; w = 1/(DELTA0 - p) ----
__global__ void k_pw(const double* e1, const double* e2, double* p, double* w){
  __shared__ double erow[DD];
  __shared__ double red[256];
  int a = blockIdx.x, tid = threadIdx.x;
  for (int k = tid; k < DD; k += 256) erow[k] = e2[a*DD + k];
  __syncthreads();
  int b = tid >> 2, sub = tid & 3;
  double acc = 0;
  for (int k = sub*128; k < sub*128 + 128; ++k) acc += e1[b*DD + k] * erow[k];
  red[tid] = acc; __syncthreads();
  if (sub == 0){
    double pv = red[tid] + red[tid+1] + red[tid+2] + red[tid+3];
    p[a*64 + b] = pv;
    w[a*64 + b] = 1.0 / (DELTA0 - pv);
  }
}

// ---- K5: totals / col-sums / row-sums of w, w*p, w*p^2 ----
__global__ void k_sums(const double* p, const double* w, double* sums){
  __shared__ double red[256*3];
  int tid = threadIdx.x;
  int a = tid >> 2, sub = tid & 3;
  double r0 = 0, r1 = 0, r2 = 0;
  for (int b = sub*16; b < sub*16 + 16; ++b){
    double wv = w[a*64 + b], pv = p[a*64 + b];
    r0 += wv; r1 += wv*pv; r2 += wv*pv*pv;
  }
  red[tid*3] = r0; red[tid*3+1] = r1; red[tid*3+2] = r2;
  __syncthreads();
  if (tid < 64){
    double t0 = 0, t1 = 0, t2 = 0;
    for (int s = 0; s < 4; ++s){
      t0 += red[(tid*4+s)*3]; t1 += red[(tid*4+s)*3+1]; t2 += red[(tid*4+s)*3+2];
    }
    sums[200 + tid] = t0; sums[200 + 64 + tid] = t1; sums[200 + 128 + tid] = t2;
  }
  __syncthreads();
  int b2 = tid >> 2;
  double c0 = 0, c1 = 0, c2 = 0;
  for (int a2 = sub*16; a2 < sub*16 + 16; ++a2){
    double wv = w[a2*64 + b2], pv = p[a2*64 + b2];
    c0 += wv; c1 += wv*pv; c2 += wv*pv*pv;
  }
  __syncthreads();
  red[tid*3] = c0; red[tid*3+1] = c1; red[tid*3+2] = c2;
  __syncthreads();
  if (tid < 64){
    double t0 = 0, t1 = 0, t2 = 0;
    for (int s = 0; s < 4; ++s){
      t0 += red[(tid*4+s)*3]; t1 += red[(tid*4+s)*3+1]; t2 += red[(tid*4+s)*3+2];
    }
    sums[8 + tid] = t0; sums[8 + 64 + tid] = t1; sums[8 + 128 + tid] = t2;
  }
  __syncthreads();
  if (tid == 0){
    double t0 = 0, t1 = 0, t2 = 0;
    for (int a3 = 0; a3 < 64; ++a3){
      t0 += sums[200 + a3]; t1 += sums[200 + 64 + a3]; t2 += sums[200 + 128 + a3];
    }
    sums[0] = t0; sums[1] = t1; sums[2] = t2;
  }
}

// ---- K6: assemble Ksmall = M^-1 + B^T diag(w) B, order [E',F',g',g,E,F] ----
__device__ __forceinline__ void decode_idx(int t, int& cls, int& pr, int& ix){
  if (t < 64)       { cls = 1; pr = 1; ix = t; }
  else if (t < 128) { cls = 2; pr = 1; ix = t - 64; }
  else if (t == 128){ cls = 0; pr = 1; ix = 0; }
  else if (t == 129){ cls = 0; pr = 0; ix = 0; }
  else if (t < 194) { cls = 1; pr = 0; ix = t - 130; }
  else              { cls = 2; pr = 0; ix = t - 194; }
}

__global__ void k_ksmall(const double* p, const double* w, const double* sums, double* Ks){
  int idx = blockIdx.x*256 + threadIdx.x;
  if (idx >= NS*NS) return;
  int r = idx / NS, c = idx % NS;
  int cr, prr, ir, cc, prc, ic;
  decode_idx(r, cr, prr, ir);
  decode_idx(c, cc, prc, ic);
  int m = prr + prc;
  double tval;
  if (cr == 0 && cc == 0)      tval = sums[m];
  else if (cr == 0 && cc == 1) tval = sums[8 + m*64 + ic];
  else if (cr == 1 && cc == 0) tval = sums[8 + m*64 + ir];
  else if (cr == 0 && cc == 2) tval = sums[200 + m*64 + ic];
  else if (cr == 2 && cc == 0) tval = sums[200 + m*64 + ir];
  else if (cr == 1 && cc == 1) tval = (ir == ic) ? sums[8 + m*64 + ir] : 0.0;
  else if (cr == 2 && cc == 2) tval = (ir == ic) ? sums[200 + m*64 + ir] : 0.0;
  else if (cr == 1 && cc == 2){
    double wv = w[ic*64 + ir], pv = p[ic*64 + ir];
    tval = (m == 0) ? wv : (m == 1) ? wv*pv : wv*pv*pv;
  } else {
    double wv = w[ir*64 + ic], pv = p[ir*64 + ic];
    tval = (m == 0) ? wv : (m == 1) ? wv*pv : wv*pv*pv;
  }
  double mv = 0.0;
  if (cr == 0 && cc == 0 && prr != prc) mv = -2.0;
  if (cr != 0 && cr == cc && ir == ic){
    if (prr != prc) mv = 2.0;
    else if (prr == 1) mv = -4.0 * RHO_;
  }
  Ks[idx] = tval + mv;
}

// ---- block Gauss-Jordan: pivot-block inversion (2 barriers/step) ----
__global__ void k_pivinv(const double* Ks, double* Pinv, int start, int m){
  __shared__ double M[64*64];
  __shared__ double rv[64], cv[64];
  int tid = threadIdx.x;
  for (int idx = tid; idx < m*m; idx += 256)
    M[(idx/m)*64 + (idx%m)] = Ks[(start + idx/m)*NS + start + idx%m];
  __syncthreads();
  for (int k = 0; k < m; ++k){
    double pk = 1.0 / M[k*64 + k];      // broadcast read, same value all threads
    if (tid < m) rv[tid] = M[k*64 + tid] * pk;
    else if (tid >= 128 && tid < 128 + m) cv[tid-128] = M[(tid-128)*64 + k];
    __syncthreads();
    for (int idx = tid; idx < m*m; idx += 256){
      int i = idx/m, j = idx%m;
      double nv;
      if (i == k)      nv = (j == k) ? pk : rv[j];
      else if (j == k) nv = -cv[i] * pk;
      else             nv = M[i*64 + j] - cv[i] * rv[j];
      M[i*64 + j] = nv;
    }
    __syncthreads();
  }
  for (int idx = tid; idx < m*m; idx += 256)
    Pinv[(idx/m)*64 + (idx%m)] = M[(idx/m)*64 + (idx%m)];
}

// ---- fused pivot row (Pinv*rows) + pivot col (cols*Pinv) ----
__global__ void k_rowcol(const double* Ks, const double* Pinv, double* temp, double* colbuf,
                         int start, int m){
  int idx = blockIdx.x*256 + threadIdx.x;
  if (idx < m*NS){
    int r = idx / NS, c = idx % NS;
    if (c >= start && c < start + m){
      temp[r*NS + c] = Pinv[r*64 + (c - start)];
    } else {
      double acc = 0;
      for (int k = 0; k < m; ++k) acc += Pinv[r*64 + k] * Ks[(start+k)*NS + c];
      temp[r*NS + c] = acc;
    }
  } else {
    int idx2 = idx - m*NS;
    if (idx2 < NS*m){
      int r = idx2 / m, kp = idx2 % m;
      if (r >= start && r < start + m) return;
      double acc = 0;
      for (int k = 0; k < m; ++k) acc += Ks[r*NS + start + k] * Pinv[k*64 + kp];
      colbuf[r*64 + kp] = -acc;
    }
  }
}

__global__ void k_trail(double* Ks, const double* temp, int start, int m){
  int idx = blockIdx.x*256 + threadIdx.x;
  if (idx >= NS*NS) return;
  int r = idx / NS, c = idx % NS;
  if (r >= start && r < start + m) return;
  if (c >= start && c < start + m) return;
  double acc = 0;
  for (int k = 0; k < m; ++k) acc += Ks[r*NS + start + k] * temp[k*NS + c];
  Ks[r*NS + c] -= acc;
}

__global__ void k_copyback(double* Ks, const double* temp, const double* colbuf, int start, int m){
  int idx = blockIdx.x*256 + threadIdx.x;
  if (idx < m*NS){
    int r = idx / NS, c = idx % NS;
    Ks[(start+r)*NS + c] = temp[r*NS + c];
  }
  int idx2 = idx - m*NS;
  if (idx2 >= 0 && idx2 < NS*m){
    int r = idx2 / m, kp = idx2 % m;
    if (!(r >= start && r < start + m)) Ks[r*NS + start + kp] = colbuf[r*64 + kp];
  }
}

// ---- cast N (= Ks after GJ, symmetric) to fp32 ----
__global__ void k_n32(const double* Ks, float* N32){
  int idx = blockIdx.x*256 + threadIdx.x;
  if (idx < NS*NS) N32[idx] = (float)Ks[idx];
}

// ---- persistent single-WG ADMM (150 iters) + fused clip/softmax epilogue ----
__global__ __launch_bounds__(1024, 4) void k_admm(const double* __restrict__ pg,
                                                  const double* __restrict__ wg,
                                                  const float* __restrict__ N32,
                                                  float* __restrict__ out){
  __shared__ double buf[NN];          // 32 KB: t, then x, reused per-iter
  __shared__ double s1[NS];
  __shared__ double s2[NS];
  __shared__ double part[4][NS];      // matvec partials
  __shared__ double cspA[16][64];
  __shared__ double cspB[16][64];
  __shared__ double y2a[64], y2b[64];

  int tid = threadIdx.x;
  int lane = tid & 63;                // b index
  int wvid = tid >> 6;                // wave id (rows 4*wvid..4*wvid+3)
  int rid = tid >> 4;                 // reduction-pass row (0..63)
  int g   = tid & 15;                 // reduction-pass sub-lane

  // per-thread register state: 4 rows a = wvid*4+q, column b = lane
  double pr[4], wr[4], xr[4], vr[4], tq[4];
  for (int q = 0; q < 4; ++q){
    int j = (wvid*4 + q)*64 + lane;
    pr[q] = pg[j]; wr[q] = wg[j];
    xr[q] = 0.0; vr[q] = 0.0;
  }
  if (tid < 64){ y2a[tid] = 0.0; y2b[tid] = 0.0; }
  __syncthreads();

  const int js0 = (tid >> 8) == 0 ? 0 : (tid >> 8) == 1 ? 65 : (tid >> 8) == 2 ? 130 : 194;
  const int js1 = (tid >> 8) == 0 ? 65 : (tid >> 8) == 1 ? 130 : (tid >> 8) == 2 ? 194 : 258;
  const int group = tid >> 8;
  const int cidx = tid & 255;

  for (int it = 0; it < NITER; ++it){
    // ---- stage 1: t = w*rhs (regs); stage t; col-sum partials ----
    double clt = 0.0, clp = 0.0;
    for (int q = 0; q < 4; ++q){
      int arow = wvid*4 + q;
      double rhs = SIG_*xr[q] + pr[q] + RHO_*fabs(vr[q])
                 + (RHO_ - y2b[lane]) + (RHO_ - y2a[arow]);
      double t = wr[q]*rhs;
      tq[q] = t;
      buf[arow*64 + lane] = t;
      clt += t; clp += pr[q]*t;
    }
    cspA[wvid][lane] = clt;
    cspB[wvid][lane] = clp;
    __syncthreads();   // B1

    // ---- sums: row sums of t & p*t via buf; col sums via csp ----
    {
      double st = 0.0, sp = 0.0;
      for (int s = 0; s < 4; ++s){
        int jj = rid*64 + g + s*16;
        double tv = buf[jj];
        st += tv; sp += pg[jj]*tv;
      }
      for (int m = 8; m >= 1; m >>= 1){
        st += __shfl_xor(st, m, 64);
        sp += __shfl_xor(sp, m, 64);
      }
      if (g == 0){ s1[194 + rid] = st; s1[64 + rid] = sp; }
      if (tid < 64){
        double sum = 0;
        for (int ww = 0; ww < 16; ++ww) sum += cspA[ww][tid];
        s1[130 + tid] = sum;
        double tot = wsum64(sum);
        if (tid == 0) s1[129] = tot;
      } else if (tid < 128){
        int b2 = tid - 64;
        double sum = 0;
        for (int ww = 0; ww < 16; ++ww) sum += cspB[ww][b2];
        s1[b2] = sum;
        double tot = wsum64(sum);
        if (tid == 64) s1[128] = tot;
      }
    }
    __syncthreads();   // B2

    // ---- matvec: s2 = N * s1, fp32 N, all 1024 threads ----
    {
      double acc = 0.0;
      for (int jj = js0; jj < js1; ++jj)
        acc += (double)N32[jj*NS + cidx] * s1[jj];
      part[group][cidx] = acc;
      if (cidx < 2){
        double acc2 = 0.0;
        int c2 = 256 + cidx;
        for (int jj = js0; jj < js1; ++jj)
          acc2 += (double)N32[jj*NS + c2] * s1[jj];
        part[group][c2] = acc2;
      }
    }
    __syncthreads();   // B3
    if (tid < NS) s2[tid] = part[0][tid] + part[1][tid] + part[2][tid] + part[3][tid];
    __syncthreads();   // B4

    // ---- stage 4: x = t - w*(B s2); v update; stage x ----
    {
      double a0 = s2[129], ap0 = s2[128];
      double sb = s2[130 + lane], spb = s2[lane];
      double clx = 0.0;
      for (int q = 0; q < 4; ++q){
        int arow = wvid*4 + q;
        double corr = a0 + sb + s2[194 + arow] + pr[q]*(ap0 + spb + s2[64 + arow]);
        double xn = tq[q] - wr[q]*corr;
        vr[q] = xn + fmin(vr[q], 0.0);
        xr[q] = xn;
        buf[arow*64 + lane] = xn;
        clx += xn;
      }
      cspA[wvid][lane] = clx;
    }
    __syncthreads();   // B5

    // ---- stage 5: dual updates from row/col sums of x ----
    {
      if (tid < 64){
        double sum = 0;
        for (int ww = 0; ww < 16; ++ww) sum += cspA[ww][tid];
        y2b[tid] += RHO_*(sum - 1.0);
      }
      double sx = 0.0;
      for (int s = 0; s < 4; ++s) sx += buf[rid*64 + g + s*16];
      for (int m = 8; m >= 1; m >>= 1) sx += __shfl_xor(sx, m, 64);
      if (g == 0) y2a[rid] += RHO_*(sx - 1.0);
    }
    __syncthreads();   // B6
  }

  // ---- epilogue: s = clip(x), softmax(ALPHA*s) over a (axis -1) ----
  for (int q = 0; q < 4; ++q){
    int i = wvid*4 + q;                   // n1 row index b
    double val = buf[lane*64 + i];        // x[a*64+b], a = lane
    val = fmin(fmax(val, 0.0), 1.0);
    double mx = wmax64(val);
    double e = exp(ALPHA_*(val - mx));
    double sm = wsum64(e);
    out[i*64 + lane] = (float)(e / sm);
  }
}

extern "C" void kernel_launch(void* const* d_in, const int* in_sizes, int n_in,
                              void* d_out, int out_size, void* d_ws, size_t ws_size,
                              hipStream_t stream){
  (void)in_sizes; (void)n_in; (void)out_size; (void)ws_size;
  const float* ft  = (const float*)d_in[0];
  const float* fd  = (const float*)d_in[1];
  const float* iou = (const float*)d_in[2];
  const float* Wm  = (const float*)d_in[3];
  const float* bb  = (const float*)d_in[4];
  char* ws = (char*)d_ws;
  double* Mp0    = (double*)(ws + OFF_MP0);
  double* nft    = (double*)(ws + OFF_NFT);
  double* nfd    = (double*)(ws + OFF_NFD);
  float*  u1     = (float*) (ws + OFF_U1);
  float*  u2     = (float*) (ws + OFF_U2);
  double* e1     = (double*)(ws + OFF_E1);
  double* e2     = (double*)(ws + OFF_E2);
  double* p      = (double*)(ws + OFF_P);
  double* w      = (double*)(ws + OFF_W);
  double* sums   = (double*)(ws + OFF_SUMS);
  double* Ks     = (double*)(ws + OFF_KS);
  double* temp   = (double*)(ws + OFF_TEMP);
  double* colbuf = (double*)(ws + OFF_COLBUF);
  double* Pinv   = (double*)(ws + OFF_PINV);
  float*  N32    = (float*) (ws + OFF_N32);

  hipLaunchKernelGGL(k_mp0,     dim3(64),  dim3(256), 0, stream, ft, fd, iou, Mp0, nft, nfd);
  hipLaunchKernelGGL(k_ubuild2, dim3(128), dim3(256), 0, stream, ft, fd, Mp0, nft, nfd, u1, u2);
  hipLaunchKernelGGL(k_egemm,   dim3(128), dim3(256), 0, stream, u1, u2, Wm, bb, e1, e2);
  hipLaunchKernelGGL(k_pw,      dim3(64),  dim3(256), 0, stream, e1, e2, p, w);
  hipLaunchKernelGGL(k_sums,    dim3(1),   dim3(256), 0, stream, p, w, sums);
  hipLaunchKernelGGL(k_ksmall,  dim3((NS*NS+255)/256), dim3(256), 0, stream, p, w, sums, Ks);

  const int starts[5] = {0, 64, 128, 130, 194};
  const int msz[5]    = {64, 64, 2, 64, 64};
  for (int pv = 0; pv < 5; ++pv){
    int s0 = starts[pv], m = msz[pv];
    hipLaunchKernelGGL(k_pivinv,   dim3(1),                 dim3(256), 0, stream, Ks, Pinv, s0, m);
    hipLaunchKernelGGL(k_rowcol,   dim3((2*m*NS+255)/256),  dim3(256), 0, stream, Ks, Pinv, temp, colbuf, s0, m);
    hipLaunchKernelGGL(k_trail,    dim3((NS*NS+255)/256),   dim3(256), 0, stream, Ks, temp, s0, m);
    hipLaunchKernelGGL(k_copyback, dim3((2*m*NS+255)/256),  dim3(256), 0, stream, Ks, temp, colbuf, s0, m);
  }
  hipLaunchKernelGGL(k_n32,  dim3((NS*NS+255)/256), dim3(256), 0, stream, Ks, N32);
  hipLaunchKernelGGL(k_admm, dim3(1), dim3(1024), 0, stream, p, w, N32, (float*)d_out);
}

// Round 3
// 3186.172 us; speedup vs baseline: 1.1405x; 1.1026x over previous
//
#include <hip/hip_runtime.h>
#include <math.h>

#define DD 512
#define NS 258
#define NWG 128
#define RHO_ 100.0
#define SIG_ 1e-3
#define ALPHA_ 200.0
#define NITER 150
#define DELTA0 (3969.0 + SIG_ + RHO_)

// ---------------- workspace byte offsets ----------------
#define OFF_BAR    0u          // unsigned cnt @0, gen @32 (memset to 0 each launch)
#define OFF_MP0    64u         // double[64*64]
#define OFF_NFT    32832u      // double[64]
#define OFF_NFD    33344u      // double[64]
#define OFF_E1     33856u      // double[64*512]
#define OFF_E2     296000u     // double[64*512]
#define OFF_P      558144u     // double[4096]
#define OFF_W      590912u     // double[4096]
#define OFF_P32    623680u     // float[4096]
#define OFF_W32    640064u     // float[4096]
#define OFF_KS     656448u     // double[258*258]
#define OFF_TEMP   1188960u    // double[64*258]
#define OFF_COLBUF 1321056u    // double[258*64]
#define OFF_OBUF   1453152u    // double[258*64]
#define OFF_N32    1585248u    // float[258*258]

// ---------------- grid barrier (hand-rolled, 128 co-resident WGs) ----------------
__device__ __forceinline__ void gsync(unsigned* cnt, unsigned* gen, unsigned& mygen){
  __syncthreads();
  if (threadIdx.x == 0){
    __threadfence();
    unsigned arrived = atomicAdd(cnt, 1u);
    if (arrived == (unsigned)(NWG - 1)){
      atomicExch(cnt, 0u);
      __threadfence();
      atomicAdd(gen, 1u);
    } else {
      while (atomicAdd(gen, 0u) == mygen) { __builtin_amdgcn_s_sleep(2); }
    }
    __threadfence();
  }
  __syncthreads();
  mygen += 1u;
}

// ---- Ksmall index decode: order [E'(0..63), F'(64..127), g'(128), g(129), E(130..193), F(194..257)]
__device__ __forceinline__ void decode_idx(int t, int& cls, int& pr, int& ix){
  if (t < 64)       { cls = 1; pr = 1; ix = t; }
  else if (t < 128) { cls = 2; pr = 1; ix = t - 64; }
  else if (t == 128){ cls = 0; pr = 1; ix = 0; }
  else if (t == 129){ cls = 0; pr = 0; ix = 0; }
  else if (t < 194) { cls = 1; pr = 0; ix = t - 130; }
  else              { cls = 2; pr = 0; ix = t - 194; }
}

// =================== K1: fused prep (everything before ADMM) ===================
__global__ __launch_bounds__(256) void k_prep(const float* __restrict__ ft,
                                              const float* __restrict__ fd,
                                              const float* __restrict__ iou,
                                              const float* __restrict__ Wm,
                                              const float* __restrict__ bb,
                                              char* ws){
  unsigned* cnt = (unsigned*)(ws + OFF_BAR);
  unsigned* gen = (unsigned*)(ws + OFF_BAR + 32);
  double* Mp0    = (double*)(ws + OFF_MP0);
  double* nft    = (double*)(ws + OFF_NFT);
  double* nfd    = (double*)(ws + OFF_NFD);
  double* e1     = (double*)(ws + OFF_E1);
  double* e2     = (double*)(ws + OFF_E2);
  double* p      = (double*)(ws + OFF_P);
  double* w      = (double*)(ws + OFF_W);
  float*  p32    = (float*) (ws + OFF_P32);
  float*  w32    = (float*) (ws + OFF_W32);
  double* Ks     = (double*)(ws + OFF_KS);
  double* temp   = (double*)(ws + OFF_TEMP);
  double* colbuf = (double*)(ws + OFF_COLBUF);
  double* obuf   = (double*)(ws + OFF_OBUF);
  float*  N32    = (float*) (ws + OFF_N32);

  __shared__ double M[64*65];     // pivot block / Pinv
  __shared__ double red[768];
  __shared__ double sumsL[392];
  __shared__ double rowf[512];    // aliased as float[1024] scratch
  __shared__ double lamS;

  int tid = threadIdx.x;
  int wg  = blockIdx.x;
  unsigned mygen = 0u;

  // ---------- P0: Mp0 = ft@fd^T + iou ; row norms (WGs 0..63) ----------
  if (wg < 64){
    int i = wg;
    float* row = (float*)rowf;
    for (int k = tid; k < DD; k += 256) row[k] = ft[i*DD + k];
    __syncthreads();
    double s = 0, s2v = 0;
    for (int k = tid; k < DD; k += 256){
      double a = row[k]; s += a*a;
      double b = fd[i*DD + k]; s2v += b*b;
    }
    red[tid] = s; __syncthreads();
    for (int o = 128; o; o >>= 1){ if (tid < o) red[tid] += red[tid+o]; __syncthreads(); }
    if (tid == 0) nft[i] = red[0];
    __syncthreads();
    red[tid] = s2v; __syncthreads();
    for (int o = 128; o; o >>= 1){ if (tid < o) red[tid] += red[tid+o]; __syncthreads(); }
    if (tid == 0) nfd[i] = red[0];
    __syncthreads();
    int j = tid >> 2, sub = tid & 3;
    double acc = 0;
    for (int k = sub*128; k < sub*128 + 128; ++k)
      acc += (double)row[k] * (double)fd[j*DD + k];
    red[tid] = acc; __syncthreads();
    if (sub == 0)
      Mp0[i*64 + j] = red[tid] + red[tid+1] + red[tid+2] + red[tid+3] + (double)iou[i*64 + j];
  }
  gsync(cnt, gen, mygen);

  // ---------- P1+P2 (fused, same WG handles same row): ubuild then egemm ----------
  {
    int which = (wg < 64) ? 1 : 2;
    int i = wg & 63;
    double* mrow = sumsL;   // 64 doubles
    if (tid < 64) mrow[tid] = (which == 1) ? Mp0[i*64 + tid] : Mp0[tid*64 + i];
    __syncthreads();
    const float* base = (which == 1) ? fd : ft;
    const float* self = (which == 1) ? ft : fd;
    const double* nrm_self = (which == 1) ? nft : nfd;
    double mv[2]; double nm = 0;
    for (int h = 0; h < 2; ++h){
      int c = tid + h*256;
      double acc = 0;
      for (int a = 0; a < 64; ++a) acc += mrow[a] * (double)base[a*DD + c];
      mv[h] = acc; nm += acc*acc;
    }
    red[tid] = nm; __syncthreads();
    for (int o = 128; o; o >>= 1){ if (tid < o) red[tid] += red[tid+o]; __syncthreads(); }
    if (tid == 0) lamS = sqrt(nrm_self[i] / red[0]);
    __syncthreads();
    double lam = lamS;
    float* urow = (float*)rowf;
    for (int h = 0; h < 2; ++h){
      int c = tid + h*256;
      urow[c] = (float)((double)self[i*DD + c] + lam * mv[h]);
    }
    __syncthreads();
    // egemm: e = l2norm(relu(u @ W^T + b)), row r = wg
    double* e = (wg < 64) ? (e1 + (size_t)wg*DD) : (e2 + (size_t)(wg-64)*DD);
    double v[2]; double nm2 = 0;
    for (int h = 0; h < 2; ++h){
      int c = tid + h*256;
      const float* wr = Wm + (size_t)c*DD;
      double acc = (double)bb[c];
      for (int k = 0; k < DD; k += 4){
        float4 wq = *(const float4*)(wr + k);
        acc += (double)urow[k]   * (double)wq.x + (double)urow[k+1] * (double)wq.y
             + (double)urow[k+2] * (double)wq.z + (double)urow[k+3] * (double)wq.w;
      }
      acc = fmax(acc, 0.0);
      v[h] = acc; nm2 += acc*acc;
    }
    red[tid] = nm2; __syncthreads();
    for (int o = 128; o; o >>= 1){ if (tid < o) red[tid] += red[tid+o]; __syncthreads(); }
    if (tid == 0) lamS = fmax(sqrt(red[0]), 1e-12);
    __syncthreads();
    double inv = 1.0 / lamS;
    for (int h = 0; h < 2; ++h) e[tid + h*256] = v[h] * inv;
  }
  gsync(cnt, gen, mygen);

  // ---------- P3: p[a*64+b] = e1[b].e2[a]; w = 1/(D0 - p) ----------
  {
    int a = wg >> 1;
    int dnum = tid >> 3, sub = tid & 7;
    int b = (wg & 1)*32 + dnum;
    const double* e1r = e1 + (size_t)b*DD;
    const double* e2r = e2 + (size_t)a*DD;
    double acc = 0;
    for (int k = sub*64; k < sub*64 + 64; ++k) acc += e1r[k] * e2r[k];
    for (int m2 = 4; m2 >= 1; m2 >>= 1) acc += __shfl_xor(acc, m2, 8);
    if (sub == 0){
      int j = a*64 + b;
      double wv = 1.0 / (DELTA0 - acc);
      p[j] = acc; w[j] = wv;
      p32[j] = (float)acc; w32[j] = (float)wv;
    }
  }
  gsync(cnt, gen, mygen);

  // ---------- P4: sums (redundant per WG, into LDS) + Ksmall assembly ----------
  {
    int a = tid >> 2, sub = tid & 3;
    double r0 = 0, r1 = 0, r2 = 0;
    for (int b = sub*16; b < sub*16 + 16; ++b){
      double wv = w[a*64 + b], pv = p[a*64 + b];
      r0 += wv; r1 += wv*pv; r2 += wv*pv*pv;
    }
    red[tid*3] = r0; red[tid*3+1] = r1; red[tid*3+2] = r2;
    __syncthreads();
    if (tid < 64){
      double t0 = 0, t1 = 0, t2 = 0;
      for (int s = 0; s < 4; ++s){
        t0 += red[(tid*4+s)*3]; t1 += red[(tid*4+s)*3+1]; t2 += red[(tid*4+s)*3+2];
      }
      sumsL[200 + tid] = t0; sumsL[200 + 64 + tid] = t1; sumsL[200 + 128 + tid] = t2;
    }
    __syncthreads();
    int b2 = tid >> 2;
    double c0 = 0, c1 = 0, c2 = 0;
    for (int a2 = sub*16; a2 < sub*16 + 16; ++a2){
      double wv = w[a2*64 + b2], pv = p[a2*64 + b2];
      c0 += wv; c1 += wv*pv; c2 += wv*pv*pv;
    }
    __syncthreads();
    red[tid*3] = c0; red[tid*3+1] = c1; red[tid*3+2] = c2;
    __syncthreads();
    if (tid < 64){
      double t0 = 0, t1 = 0, t2 = 0;
      for (int s = 0; s < 4; ++s){
        t0 += red[(tid*4+s)*3]; t1 += red[(tid*4+s)*3+1]; t2 += red[(tid*4+s)*3+2];
      }
      sumsL[8 + tid] = t0; sumsL[8 + 64 + tid] = t1; sumsL[8 + 128 + tid] = t2;
    }
    __syncthreads();
    if (tid == 0){
      double t0 = 0, t1 = 0, t2 = 0;
      for (int a3 = 0; a3 < 64; ++a3){
        t0 += sumsL[200 + a3]; t1 += sumsL[200 + 64 + a3]; t2 += sumsL[200 + 128 + a3];
      }
      sumsL[0] = t0; sumsL[1] = t1; sumsL[2] = t2;
    }
    __syncthreads();
    // Ksmall assembly (strided over grid)
    for (int idx = wg*256 + tid; idx < NS*NS; idx += NWG*256){
      int r = idx / NS, c = idx % NS;
      int cr, prr, ir, cc, prc, ic;
      decode_idx(r, cr, prr, ir);
      decode_idx(c, cc, prc, ic);
      int m = prr + prc;
      double tval;
      if (cr == 0 && cc == 0)      tval = sumsL[m];
      else if (cr == 0 && cc == 1) tval = sumsL[8 + m*64 + ic];
      else if (cr == 1 && cc == 0) tval = sumsL[8 + m*64 + ir];
      else if (cr == 0 && cc == 2) tval = sumsL[200 + m*64 + ic];
      else if (cr == 2 && cc == 0) tval = sumsL[200 + m*64 + ir];
      else if (cr == 1 && cc == 1) tval = (ir == ic) ? sumsL[8 + m*64 + ir] : 0.0;
      else if (cr == 2 && cc == 2) tval = (ir == ic) ? sumsL[200 + m*64 + ir] : 0.0;
      else if (cr == 1 && cc == 2){
        double wv = w[ic*64 + ir], pv = p[ic*64 + ir];
        tval = (m == 0) ? wv : (m == 1) ? wv*pv : wv*pv*pv;
      } else {
        double wv = w[ir*64 + ic], pv = p[ir*64 + ic];
        tval = (m == 0) ? wv : (m == 1) ? wv*pv : wv*pv*pv;
      }
      double mv2 = 0.0;
      if (cr == 0 && cc == 0 && prr != prc) mv2 = -2.0;
      if (cr != 0 && cr == cc && ir == ic){
        if (prr != prc) mv2 = 2.0;
        else if (prr == 1) mv2 = -4.0 * RHO_;
      }
      Ks[idx] = tval + mv2;
    }
  }
  gsync(cnt, gen, mygen);

  // ---------- P5: block Gauss-Jordan, pivots [E'(diag), F', g'g, E, F] ----------
  const int starts[5] = {0, 64, 128, 130, 194};
  const int msz[5]    = {64, 64, 2, 64, 64};
  for (int pv = 0; pv < 5; ++pv){
    int s0 = starts[pv], m = msz[pv];
    // --- pivot-block inverse into M (WG-redundant) ---
    if (pv == 0){
      // E'E' block is exactly diagonal
      for (int idx = tid; idx < 64*64; idx += 256){
        int i2 = idx >> 6, j2 = idx & 63;
        M[i2*65 + j2] = (i2 == j2) ? 1.0 / Ks[(s0+i2)*NS + s0+i2] : 0.0;
      }
      __syncthreads();
    } else {
      for (int idx = tid; idx < m*m; idx += 256)
        M[(idx/m)*65 + (idx%m)] = Ks[(s0 + idx/m)*NS + s0 + idx%m];
      __syncthreads();
      for (int k = 0; k < m; ++k){
        double pk = 1.0 / M[k*65 + k];
        if (tid < m) red[tid] = M[k*65 + tid] * pk;                     // rv
        else if (tid >= 128 && tid < 128 + m) red[64 + tid-128] = M[(tid-128)*65 + k]; // cv
        __syncthreads();
        for (int idx = tid; idx < m*m; idx += 256){
          int i2 = idx/m, j2 = idx%m;
          double nv;
          if (i2 == k)      nv = (j2 == k) ? pk : red[j2];
          else if (j2 == k) nv = -red[64 + i2] * pk;
          else              nv = M[i2*65 + j2] - red[64 + i2] * red[j2];
          M[i2*65 + j2] = nv;
        }
        __syncthreads();
      }
    }
    // --- rowcol: temp = Pinv*rows ; obuf = old cols ; colbuf = -cols*Pinv ---
    for (int idx = wg*256 + tid; idx < m*NS; idx += NWG*256){
      int r = idx / NS, c2 = idx % NS;
      double v;
      if (c2 >= s0 && c2 < s0 + m) v = M[r*65 + (c2 - s0)];
      else {
        double acc = 0;
        for (int k = 0; k < m; ++k) acc += M[r*65 + k] * Ks[(s0+k)*NS + c2];
        v = acc;
      }
      temp[r*NS + c2] = v;
    }
    for (int idx = wg*256 + tid; idx < NS*m; idx += NWG*256){
      int r = idx / m, kp = idx % m;
      if (r < s0 || r >= s0 + m){
        obuf[r*64 + kp] = Ks[r*NS + s0 + kp];
        double acc = 0;
        for (int k = 0; k < m; ++k) acc += Ks[r*NS + s0 + k] * M[k*65 + kp];
        colbuf[r*64 + kp] = -acc;
      }
    }
    gsync(cnt, gen, mygen);
    // --- trail + copyback (disjoint regions; dual-write N32 on last pivot) ---
    int nm = NS - m;
    for (int idx = wg*256 + tid; idx < nm*nm; idx += NWG*256){
      int rr = idx / nm, cc2 = idx % nm;
      int r  = rr  + (rr  >= s0 ? m : 0);
      int c2 = cc2 + (cc2 >= s0 ? m : 0);
      double acc = 0;
      for (int k = 0; k < m; ++k) acc += obuf[r*64 + k] * temp[k*NS + c2];
      double nv = Ks[r*NS + c2] - acc;
      Ks[r*NS + c2] = nv;
      if (pv == 4) N32[r*NS + c2] = (float)nv;
    }
    for (int idx = wg*256 + tid; idx < m*NS; idx += NWG*256){
      int r = idx / NS, c2 = idx % NS;
      double v = temp[r*NS + c2];
      Ks[(s0+r)*NS + c2] = v;
      if (pv == 4) N32[(s0+r)*NS + c2] = (float)v;
    }
    for (int idx = wg*256 + tid; idx < NS*m; idx += NWG*256){
      int r = idx / m, kp = idx % m;
      if (r < s0 || r >= s0 + m){
        double v = colbuf[r*64 + kp];
        Ks[r*NS + s0 + kp] = v;
        if (pv == 4) N32[r*NS + s0 + kp] = (float)v;
      }
    }
    gsync(cnt, gen, mygen);
  }
}

// =================== K2: persistent single-WG ADMM + softmax ===================
__global__ __launch_bounds__(1024) void k_admm(const float* __restrict__ N32,
                                               const float* __restrict__ p32,
                                               const float* __restrict__ w32,
                                               float* __restrict__ out){
  __shared__ float tbuf[64*65];
  __shared__ float pbuf[64*65];
  __shared__ float cspT[16][64];
  __shared__ float cspPT[16][64];
  __shared__ float cspX[16][64];
  __shared__ __align__(16) double s1g[4][68];   // per-group aligned s1 slices
  __shared__ __align__(16) double s1f[260];     // flat s1 (extra-col path)
  __shared__ __align__(16) double s2[260];

  int tid  = threadIdx.x;
  int lane = tid & 63;          // b
  int wvid = tid >> 6;          // wave -> rows 4*wvid..+3
  int group = tid >> 8;         // matvec jj-group
  int c     = tid & 255;        // matvec column

  // ---- register cache of N (fp32): 68 values/thread, groups of 65 jj (padded) ----
  float nc[68];
#pragma unroll
  for (int k = 0; k < 68; ++k){
    int jj = 65*group + k;
    nc[k] = (k < 65 && jj < 258) ? N32[jj*NS + c] : 0.f;
  }

  // ---- state ----
  float pr[4], wr[4], xr[4], vr[4], tq[4];
  double y2a[4]; double y2b = 0.0;
#pragma unroll
  for (int q = 0; q < 4; ++q){
    int arow = wvid*4 + q;
    int j = arow*64 + lane;
    pr[q] = p32[j]; wr[q] = w32[j];
    xr[q] = 0.f; vr[q] = 0.f; tq[q] = 0.f; y2a[q] = 0.0;
    pbuf[arow*65 + lane] = pr[q];
  }
  // zero never-written s1 slots (avoid NaN*0 from LDS garbage)
  if (tid < 20) s1g[tid/5][63 + (tid%5)] = 0.0;   // covers pads; live slots rewritten each iter
  if (tid >= 256 && tid < 260) s1f[tid] = 0.0;
  __syncthreads();

  const int rid = tid >> 4, gg = tid & 15;

  for (int it = 0; it < NITER; ++it){
    // ================= stage 1: y2b update, t = w*rhs =================
    if (it){
      float csx = 0.f;
#pragma unroll
      for (int w2 = 0; w2 < 16; ++w2) csx += cspX[w2][lane];
      y2b += RHO_ * ((double)csx - 1.0);
    }
    double cb = RHO_ - y2b;
    double clt = 0.0, clp = 0.0;
#pragma unroll
    for (int q = 0; q < 4; ++q){
      int arow = wvid*4 + q;
      double rhs = SIG_*(double)xr[q] + (double)pr[q] + RHO_*fabs((double)vr[q])
                 + cb + (RHO_ - y2a[q]);
      double t = (double)wr[q] * rhs;
      tq[q] = (float)t;
      tbuf[arow*65 + lane] = (float)t;
      clt += t; clp += (double)pr[q]*t;
    }
    cspT[wvid][lane]  = (float)clt;
    cspPT[wvid][lane] = (float)clp;
    if (tid < 260) s2[tid] = 0.0;
    __syncthreads();  // B1

    // ================= stage 2: build s1 (row/col sums, f64) =================
    {
      double st = 0.0, sp = 0.0;
#pragma unroll
      for (int s = 0; s < 4; ++s){
        int col = gg + s*16;
        double tv = (double)tbuf[rid*65 + col];
        st += tv; sp += (double)pbuf[rid*65 + col]*tv;
      }
#pragma unroll
      for (int m2 = 8; m2 >= 1; m2 >>= 1){
        st += __shfl_xor(st, m2, 16);
        sp += __shfl_xor(sp, m2, 16);
      }
      if (gg == 0){
        int jt = 194 + rid; int gt = (jt >= 195) ? 3 : 2;
        s1g[gt][jt - 65*gt] = st; s1f[jt] = st;
        int jp = 64 + rid;  int gp = (jp >= 65) ? 1 : 0;
        s1g[gp][jp - 65*gp] = sp; s1f[jp] = sp;
      }
      if (tid < 128){
        int b2 = tid & 63;
        double cs = 0.0;
        if (tid < 64){
#pragma unroll
          for (int w2 = 0; w2 < 16; ++w2) cs += (double)cspT[w2][b2];
          s1g[2][b2] = cs; s1f[130 + b2] = cs;
        } else {
#pragma unroll
          for (int w2 = 0; w2 < 16; ++w2) cs += (double)cspPT[w2][b2];
          s1g[0][b2] = cs; s1f[b2] = cs;
        }
        double tot = cs;
#pragma unroll
        for (int m2 = 32; m2 >= 1; m2 >>= 1) tot += __shfl_xor(tot, m2, 64);
        if (b2 == 0){
          if (tid < 64){ s1g[1][64] = tot; s1f[129] = tot; }   // total t  -> jj 129
          else         { s1g[1][63] = tot; s1f[128] = tot; }   // total pt -> jj 128
        }
      }
    }
    __syncthreads();  // B2

    // ================= matvec: s2 = N*s1 (register N, fp32*f64) =================
    {
      double acc0 = 0.0, acc1 = 0.0;
#pragma unroll
      for (int m2 = 0; m2 < 17; ++m2){
        const double2 a = *(const double2*)&s1g[group][4*m2];
        const double2 b = *(const double2*)&s1g[group][4*m2 + 2];
        acc0 += (double)nc[4*m2]   * a.x + (double)nc[4*m2+2] * b.x;
        acc1 += (double)nc[4*m2+1] * a.y + (double)nc[4*m2+3] * b.y;
      }
      atomicAdd(&s2[c], acc0 + acc1);
      if (wvid < 2){   // columns 256,257 via symmetric rows of N
        double e = 0.0;
#pragma unroll
        for (int k2 = 0; k2 < 5; ++k2){
          int jj = lane + 64*k2;
          if (jj < 258) e += (double)N32[(256 + wvid)*NS + jj] * s1f[jj];
        }
#pragma unroll
        for (int m2 = 32; m2 >= 1; m2 >>= 1) e += __shfl_xor(e, m2, 64);
        if (lane == 0) s2[256 + wvid] = e;
      }
    }
    __syncthreads();  // B3

    // ================= stage 4: x update, v update, y2a, x-col partials =================
    {
      const double2 sgg = *(const double2*)&s2[128];          // .x=alphap, .y=alpha
      double sb  = s2[130 + lane];
      double spb = s2[lane];
      const double2 sraA = *(const double2*)&s2[194 + 4*wvid];
      const double2 sraB = *(const double2*)&s2[196 + 4*wvid];
      const double2 srpA = *(const double2*)&s2[64 + 4*wvid];
      const double2 srpB = *(const double2*)&s2[66 + 4*wvid];
      double sra[4] = {sraA.x, sraA.y, sraB.x, sraB.y};
      double srp[4] = {srpA.x, srpA.y, srpB.x, srpB.y};
      double clx = 0.0;
#pragma unroll
      for (int q = 0; q < 4; ++q){
        double corr = sgg.y + sb + sra[q] + (double)pr[q]*(sgg.x + spb + srp[q]);
        double xn = (double)tq[q] - (double)wr[q]*corr;
        vr[q] = (float)(xn + fmin((double)vr[q], 0.0));
        xr[q] = (float)xn;
        float rsx = (float)xn;
#pragma unroll
        for (int m2 = 32; m2 >= 1; m2 >>= 1) rsx += __shfl_xor(rsx, m2, 64);
        y2a[q] += RHO_*((double)rsx - 1.0);
        clx += xn;
        if (it == NITER-1) tbuf[(wvid*4+q)*65 + lane] = (float)xn;
      }
      cspX[wvid][lane] = (float)clx;
    }
    __syncthreads();  // B4
  }

  // ================= epilogue: clip + softmax(ALPHA*s, axis=-1) =================
#pragma unroll
  for (int q = 0; q < 4; ++q){
    int i = wvid*4 + q;                     // n1 row index
    double val = (double)tbuf[lane*65 + i]; // x[a=lane][b=i]
    val = fmin(fmax(val, 0.0), 1.0);
    double mx = val;
#pragma unroll
    for (int m2 = 32; m2 >= 1; m2 >>= 1) mx = fmax(mx, __shfl_xor(mx, m2, 64));
    double e = exp(ALPHA_*(val - mx));
    double sm = e;
#pragma unroll
    for (int m2 = 32; m2 >= 1; m2 >>= 1) sm += __shfl_xor(sm, m2, 64);
    out[i*64 + lane] = (float)(e/sm);
  }
}

extern "C" void kernel_launch(void* const* d_in, const int* in_sizes, int n_in,
                              void* d_out, int out_size, void* d_ws, size_t ws_size,
                              hipStream_t stream){
  (void)in_sizes; (void)n_in; (void)out_size; (void)ws_size;
  const float* ft  = (const float*)d_in[0];
  const float* fd  = (const float*)d_in[1];
  const float* iou = (const float*)d_in[2];
  const float* Wm  = (const float*)d_in[3];
  const float* bb  = (const float*)d_in[4];
  char* ws = (char*)d_ws;

  // zero the grid-barrier counters (ws is poisoned 0xAA before every launch)
  hipMemsetAsync(ws + OFF_BAR, 0, 64, stream);

  hipLaunchKernelGGL(k_prep, dim3(NWG), dim3(256), 0, stream, ft, fd, iou, Wm, bb, ws);

  const float* N32 = (const float*)(ws + OFF_N32);
  const float* p32 = (const float*)(ws + OFF_P32);
  const float* w32 = (const float*)(ws + OFF_W32);
  hipLaunchKernelGGL(k_admm, dim3(1), dim3(1024), 0, stream, N32, p32, w32, (float*)d_out);
}

// Round 5
// 2046.606 us; speedup vs baseline: 1.7755x; 1.5568x over previous
//
#include <hip/hip_runtime.h>
#include <math.h>

#define DD 512
#define NS 258
#define NSP 264
#define NWG 128
#define RHO_ 100.0
#define SIG_ 1e-3
#define ALPHA_ 200.0
#define NITER 150
#define DELTA0 (3969.0 + SIG_ + RHO_)

// ---------------- workspace byte offsets ----------------
#define OFF_BAR    0u          // unsigned cnt @0, gen @32 (memset to 0 each launch)
#define OFF_MP0    64u         // double[64*64]
#define OFF_NFT    32832u      // double[64]
#define OFF_NFD    33344u      // double[64]
#define OFF_E1     33856u      // double[64*512]
#define OFF_E2     296000u     // double[64*512]
#define OFF_P      558144u     // double[4096]
#define OFF_W      590912u     // double[4096]
#define OFF_P32    623680u     // float[4096]
#define OFF_W32    640064u     // float[4096]
#define OFF_KS     656448u     // double[258*258]
#define OFF_TEMP   1188960u    // double[64*258]
#define OFF_COLBUF 1321056u    // double[258*64]
#define OFF_OBUF   1453152u    // double[258*64]
#define OFF_N32    1585248u    // float[264*264] padded, PERMUTED ordering

// permutation: GJ ordering [E',F',g'(128),g(129),E(130..193),F(194..257)]
//          ->  admm ordering [E'(0..63),F'(64..127),E(128..191),F(192..255),g'(256),g(257)]
__device__ __forceinline__ int perm258(int i){
  return (i < 128) ? i : (i == 128) ? 256 : (i == 129) ? 257 : (i - 2);
}

// ---------------- DPP reduction helpers (fp32, VALU pipe) ----------------
template<int CTRL>
__device__ __forceinline__ float dppadd(float v){
  int t = __builtin_amdgcn_mov_dpp(__float_as_int(v), CTRL, 0xF, 0xF, 1);
  return v + __int_as_float(t);
}
template<int CTRL>
__device__ __forceinline__ float dppmax(float v){
  int t = __builtin_amdgcn_mov_dpp(__float_as_int(v), CTRL, 0xF, 0xF, 1);
  return fmaxf(v, __int_as_float(t));
}
__device__ __forceinline__ float sum16(float v){
  v = dppadd<0xB1>(v);   // quad_perm xor1
  v = dppadd<0x4E>(v);   // quad_perm xor2
  v = dppadd<0x124>(v);  // row_ror:4
  v = dppadd<0x128>(v);  // row_ror:8
  return v;
}
__device__ __forceinline__ float wsum64f(float v){
  v = sum16(v);
  v += __shfl_xor(v, 16, 64);
  v += __shfl_xor(v, 32, 64);
  return v;
}
__device__ __forceinline__ float wmax64f(float v){
  v = dppmax<0xB1>(v); v = dppmax<0x4E>(v); v = dppmax<0x124>(v); v = dppmax<0x128>(v);
  v = fmaxf(v, __shfl_xor(v, 16, 64));
  v = fmaxf(v, __shfl_xor(v, 32, 64));
  return v;
}

// ---------------- grid barrier (hand-rolled, 128 co-resident WGs) ----------------
__device__ __forceinline__ void gsync(unsigned* cnt, unsigned* gen, unsigned& mygen){
  __syncthreads();
  if (threadIdx.x == 0){
    __threadfence();
    unsigned arrived = atomicAdd(cnt, 1u);
    if (arrived == (unsigned)(NWG - 1)){
      atomicExch(cnt, 0u);
      __threadfence();
      atomicAdd(gen, 1u);
    } else {
      while (atomicAdd(gen, 0u) == mygen) { __builtin_amdgcn_s_sleep(8); }
    }
    __threadfence();
  }
  __syncthreads();
  mygen += 1u;
}

// ---- Ksmall index decode: order [E'(0..63), F'(64..127), g'(128), g(129), E(130..193), F(194..257)]
__device__ __forceinline__ void decode_idx(int t, int& cls, int& pr, int& ix){
  if (t < 64)       { cls = 1; pr = 1; ix = t; }
  else if (t < 128) { cls = 2; pr = 1; ix = t - 64; }
  else if (t == 128){ cls = 0; pr = 1; ix = 0; }
  else if (t == 129){ cls = 0; pr = 0; ix = 0; }
  else if (t < 194) { cls = 1; pr = 0; ix = t - 130; }
  else              { cls = 2; pr = 0; ix = t - 194; }
}

// =================== K1: fused prep (everything before ADMM) ===================
__global__ __launch_bounds__(256) void k_prep(const float* __restrict__ ft,
                                              const float* __restrict__ fd,
                                              const float* __restrict__ iou,
                                              const float* __restrict__ Wm,
                                              const float* __restrict__ bb,
                                              char* ws){
  unsigned* cnt = (unsigned*)(ws + OFF_BAR);
  unsigned* gen = (unsigned*)(ws + OFF_BAR + 32);
  double* Mp0    = (double*)(ws + OFF_MP0);
  double* nft    = (double*)(ws + OFF_NFT);
  double* nfd    = (double*)(ws + OFF_NFD);
  double* e1     = (double*)(ws + OFF_E1);
  double* e2     = (double*)(ws + OFF_E2);
  double* p      = (double*)(ws + OFF_P);
  double* w      = (double*)(ws + OFF_W);
  float*  p32    = (float*) (ws + OFF_P32);
  float*  w32    = (float*) (ws + OFF_W32);
  double* Ks     = (double*)(ws + OFF_KS);
  double* temp   = (double*)(ws + OFF_TEMP);
  double* colbuf = (double*)(ws + OFF_COLBUF);
  double* obuf   = (double*)(ws + OFF_OBUF);
  float*  N32    = (float*) (ws + OFF_N32);

  __shared__ double M[64*65];     // pivot block / Pinv
  __shared__ double red[768];
  __shared__ double sumsL[392];
  __shared__ double rowf[512];    // aliased as float[1024] scratch
  __shared__ double lamS;

  int tid = threadIdx.x;
  int wg  = blockIdx.x;
  unsigned mygen = 0u;

  // ---------- P0: Mp0 = ft@fd^T + iou ; row norms (WGs 0..63) ----------
  if (wg < 64){
    int i = wg;
    float* row = (float*)rowf;
    for (int k = tid; k < DD; k += 256) row[k] = ft[i*DD + k];
    __syncthreads();
    double s = 0, s2v = 0;
    for (int k = tid; k < DD; k += 256){
      double a = row[k]; s += a*a;
      double b = fd[i*DD + k]; s2v += b*b;
    }
    red[tid] = s; __syncthreads();
    for (int o = 128; o; o >>= 1){ if (tid < o) red[tid] += red[tid+o]; __syncthreads(); }
    if (tid == 0) nft[i] = red[0];
    __syncthreads();
    red[tid] = s2v; __syncthreads();
    for (int o = 128; o; o >>= 1){ if (tid < o) red[tid] += red[tid+o]; __syncthreads(); }
    if (tid == 0) nfd[i] = red[0];
    __syncthreads();
    int j = tid >> 2, sub = tid & 3;
    double acc = 0;
    for (int k = sub*128; k < sub*128 + 128; ++k)
      acc += (double)row[k] * (double)fd[j*DD + k];
    red[tid] = acc; __syncthreads();
    if (sub == 0)
      Mp0[i*64 + j] = red[tid] + red[tid+1] + red[tid+2] + red[tid+3] + (double)iou[i*64 + j];
  }
  gsync(cnt, gen, mygen);

  // ---------- P1+P2: ubuild then egemm ----------
  {
    int which = (wg < 64) ? 1 : 2;
    int i = wg & 63;
    double* mrow = sumsL;
    if (tid < 64) mrow[tid] = (which == 1) ? Mp0[i*64 + tid] : Mp0[tid*64 + i];
    __syncthreads();
    const float* base = (which == 1) ? fd : ft;
    const float* self = (which == 1) ? ft : fd;
    const double* nrm_self = (which == 1) ? nft : nfd;
    double mv[2]; double nm = 0;
    for (int h = 0; h < 2; ++h){
      int c = tid + h*256;
      double acc = 0;
      for (int a = 0; a < 64; ++a) acc += mrow[a] * (double)base[a*DD + c];
      mv[h] = acc; nm += acc*acc;
    }
    red[tid] = nm; __syncthreads();
    for (int o = 128; o; o >>= 1){ if (tid < o) red[tid] += red[tid+o]; __syncthreads(); }
    if (tid == 0) lamS = sqrt(nrm_self[i] / red[0]);
    __syncthreads();
    double lam = lamS;
    float* urow = (float*)rowf;
    for (int h = 0; h < 2; ++h){
      int c = tid + h*256;
      urow[c] = (float)((double)self[i*DD + c] + lam * mv[h]);
    }
    __syncthreads();
    double* e = (wg < 64) ? (e1 + (size_t)wg*DD) : (e2 + (size_t)(wg-64)*DD);
    double v[2]; double nm2 = 0;
    for (int h = 0; h < 2; ++h){
      int c = tid + h*256;
      const float* wr = Wm + (size_t)c*DD;
      double acc = (double)bb[c];
      for (int k = 0; k < DD; k += 4){
        float4 wq = *(const float4*)(wr + k);
        acc += (double)urow[k]   * (double)wq.x + (double)urow[k+1] * (double)wq.y
             + (double)urow[k+2] * (double)wq.z + (double)urow[k+3] * (double)wq.w;
      }
      acc = fmax(acc, 0.0);
      v[h] = acc; nm2 += acc*acc;
    }
    red[tid] = nm2; __syncthreads();
    for (int o = 128; o; o >>= 1){ if (tid < o) red[tid] += red[tid+o]; __syncthreads(); }
    if (tid == 0) lamS = fmax(sqrt(red[0]), 1e-12);
    __syncthreads();
    double inv = 1.0 / lamS;
    for (int h = 0; h < 2; ++h) e[tid + h*256] = v[h] * inv;
  }
  gsync(cnt, gen, mygen);

  // ---------- P3: p[a*64+b] = e1[b].e2[a]; w = 1/(D0 - p) ----------
  {
    int a = wg >> 1;
    int dnum = tid >> 3, sub = tid & 7;
    int b = (wg & 1)*32 + dnum;
    const double* e1r = e1 + (size_t)b*DD;
    const double* e2r = e2 + (size_t)a*DD;
    double acc = 0;
    for (int k = sub*64; k < sub*64 + 64; ++k) acc += e1r[k] * e2r[k];
    for (int m2 = 4; m2 >= 1; m2 >>= 1) acc += __shfl_xor(acc, m2, 8);
    if (sub == 0){
      int j = a*64 + b;
      double wv = 1.0 / (DELTA0 - acc);
      p[j] = acc; w[j] = wv;
      p32[j] = (float)acc; w32[j] = (float)wv;
    }
  }
  gsync(cnt, gen, mygen);

  // ---------- P4: sums (redundant per WG) + Ksmall assembly ----------
  {
    int a = tid >> 2, sub = tid & 3;
    double r0 = 0, r1 = 0, r2 = 0;
    for (int b = sub*16; b < sub*16 + 16; ++b){
      double wv = w[a*64 + b], pv = p[a*64 + b];
      r0 += wv; r1 += wv*pv; r2 += wv*pv*pv;
    }
    red[tid*3] = r0; red[tid*3+1] = r1; red[tid*3+2] = r2;
    __syncthreads();
    if (tid < 64){
      double t0 = 0, t1 = 0, t2 = 0;
      for (int s = 0; s < 4; ++s){
        t0 += red[(tid*4+s)*3]; t1 += red[(tid*4+s)*3+1]; t2 += red[(tid*4+s)*3+2];
      }
      sumsL[200 + tid] = t0; sumsL[200 + 64 + tid] = t1; sumsL[200 + 128 + tid] = t2;
    }
    __syncthreads();
    int b2 = tid >> 2;
    double c0 = 0, c1 = 0, c2 = 0;
    for (int a2 = sub*16; a2 < sub*16 + 16; ++a2){
      double wv = w[a2*64 + b2], pv = p[a2*64 + b2];
      c0 += wv; c1 += wv*pv; c2 += wv*pv*pv;
    }
    __syncthreads();
    red[tid*3] = c0; red[tid*3+1] = c1; red[tid*3+2] = c2;
    __syncthreads();
    if (tid < 64){
      double t0 = 0, t1 = 0, t2 = 0;
      for (int s = 0; s < 4; ++s){
        t0 += red[(tid*4+s)*3]; t1 += red[(tid*4+s)*3+1]; t2 += red[(tid*4+s)*3+2];
      }
      sumsL[8 + tid] = t0; sumsL[8 + 64 + tid] = t1; sumsL[8 + 128 + tid] = t2;
    }
    __syncthreads();
    if (tid == 0){
      double t0 = 0, t1 = 0, t2 = 0;
      for (int a3 = 0; a3 < 64; ++a3){
        t0 += sumsL[200 + a3]; t1 += sumsL[200 + 64 + a3]; t2 += sumsL[200 + 128 + a3];
      }
      sumsL[0] = t0; sumsL[1] = t1; sumsL[2] = t2;
    }
    __syncthreads();
    for (int idx = wg*256 + tid; idx < NS*NS; idx += NWG*256){
      int r = idx / NS, c = idx % NS;
      int cr, prr, ir, cc, prc, ic;
      decode_idx(r, cr, prr, ir);
      decode_idx(c, cc, prc, ic);
      int m = prr + prc;
      double tval;
      if (cr == 0 && cc == 0)      tval = sumsL[m];
      else if (cr == 0 && cc == 1) tval = sumsL[8 + m*64 + ic];
      else if (cr == 1 && cc == 0) tval = sumsL[8 + m*64 + ir];
      else if (cr == 0 && cc == 2) tval = sumsL[200 + m*64 + ic];
      else if (cr == 2 && cc == 0) tval = sumsL[200 + m*64 + ir];
      else if (cr == 1 && cc == 1) tval = (ir == ic) ? sumsL[8 + m*64 + ir] : 0.0;
      else if (cr == 2 && cc == 2) tval = (ir == ic) ? sumsL[200 + m*64 + ir] : 0.0;
      else if (cr == 1 && cc == 2){
        double wv = w[ic*64 + ir], pv = p[ic*64 + ir];
        tval = (m == 0) ? wv : (m == 1) ? wv*pv : wv*pv*pv;
      } else {
        double wv = w[ir*64 + ic], pv = p[ir*64 + ic];
        tval = (m == 0) ? wv : (m == 1) ? wv*pv : wv*pv*pv;
      }
      double mv2 = 0.0;
      if (cr == 0 && cc == 0 && prr != prc) mv2 = -2.0;
      if (cr != 0 && cr == cc && ir == ic){
        if (prr != prc) mv2 = 2.0;
        else if (prr == 1) mv2 = -4.0 * RHO_;
      }
      Ks[idx] = tval + mv2;
    }
  }
  gsync(cnt, gen, mygen);

  // ---------- P5: block Gauss-Jordan, pivots [E'(diag), F', g'g, E, F] ----------
  const int starts[5] = {0, 64, 128, 130, 194};
  const int msz[5]    = {64, 64, 2, 64, 64};
  for (int pv = 0; pv < 5; ++pv){
    int s0 = starts[pv], m = msz[pv];
    if (pv == 0){
      for (int idx = tid; idx < 64*64; idx += 256){
        int i2 = idx >> 6, j2 = idx & 63;
        M[i2*65 + j2] = (i2 == j2) ? 1.0 / Ks[(s0+i2)*NS + s0+i2] : 0.0;
      }
      __syncthreads();
    } else {
      for (int idx = tid; idx < m*m; idx += 256)
        M[(idx/m)*65 + (idx%m)] = Ks[(s0 + idx/m)*NS + s0 + idx%m];
      __syncthreads();
      for (int k = 0; k < m; ++k){
        double pk = 1.0 / M[k*65 + k];
        if (tid < m) red[tid] = M[k*65 + tid] * pk;
        else if (tid >= 128 && tid < 128 + m) red[64 + tid-128] = M[(tid-128)*65 + k];
        __syncthreads();
        for (int idx = tid; idx < m*m; idx += 256){
          int i2 = idx/m, j2 = idx%m;
          double nv;
          if (i2 == k)      nv = (j2 == k) ? pk : red[j2];
          else if (j2 == k) nv = -red[64 + i2] * pk;
          else              nv = M[i2*65 + j2] - red[64 + i2] * red[j2];
          M[i2*65 + j2] = nv;
        }
        __syncthreads();
      }
    }
    for (int idx = wg*256 + tid; idx < m*NS; idx += NWG*256){
      int r = idx / NS, c2 = idx % NS;
      double v;
      if (c2 >= s0 && c2 < s0 + m) v = M[r*65 + (c2 - s0)];
      else {
        double acc = 0;
        for (int k = 0; k < m; ++k) acc += M[r*65 + k] * Ks[(s0+k)*NS + c2];
        v = acc;
      }
      temp[r*NS + c2] = v;
    }
    for (int idx = wg*256 + tid; idx < NS*m; idx += NWG*256){
      int r = idx / m, kp = idx % m;
      if (r < s0 || r >= s0 + m){
        obuf[r*64 + kp] = Ks[r*NS + s0 + kp];
        double acc = 0;
        for (int k = 0; k < m; ++k) acc += Ks[r*NS + s0 + k] * M[k*65 + kp];
        colbuf[r*64 + kp] = -acc;
      }
    }
    gsync(cnt, gen, mygen);
    int nm = NS - m;
    for (int idx = wg*256 + tid; idx < nm*nm; idx += NWG*256){
      int rr = idx / nm, cc2 = idx % nm;
      int r  = rr  + (rr  >= s0 ? m : 0);
      int c2 = cc2 + (cc2 >= s0 ? m : 0);
      double acc = 0;
      for (int k = 0; k < m; ++k) acc += obuf[r*64 + k] * temp[k*NS + c2];
      double nv = Ks[r*NS + c2] - acc;
      Ks[r*NS + c2] = nv;
      if (pv == 4) N32[perm258(r)*NSP + perm258(c2)] = (float)nv;
    }
    for (int idx = wg*256 + tid; idx < m*NS; idx += NWG*256){
      int r = idx / NS, c2 = idx % NS;
      double v = temp[r*NS + c2];
      Ks[(s0+r)*NS + c2] = v;
      if (pv == 4) N32[perm258(s0+r)*NSP + perm258(c2)] = (float)v;
    }
    for (int idx = wg*256 + tid; idx < NS*m; idx += NWG*256){
      int r = idx / m, kp = idx % m;
      if (r < s0 || r >= s0 + m){
        double v = colbuf[r*64 + kp];
        Ks[r*NS + s0 + kp] = v;
        if (pv == 4) N32[perm258(r)*NSP + perm258(s0 + kp)] = (float)v;
      }
    }
    gsync(cnt, gen, mygen);
  }
}

// =================== K2: persistent single-WG ADMM + softmax ===================
// s1/s2 admm ordering: [0..63]=cs(pt) E', [64..127]=rs(pt) F', [128..191]=cs(t) E,
// [192..255]=rs(t) F, [256]=tot(pt) g', [257]=tot(t) g
__global__ __launch_bounds__(1024, 4) void k_admm(const float* __restrict__ N32,
                                                  const float* __restrict__ p32,
                                                  const float* __restrict__ w32,
                                                  float* __restrict__ out){
  __shared__ float2 tb[64][66];       // (t, p*t) staging; reused for x^T at end
  __shared__ float2 csTP[64][18];     // col-sum partials (t, p*t) per (b, wave)
  __shared__ float  csXl[64][18];     // col-sum partials of x per (b, wave)
  __shared__ __align__(16) float  s1f[264];
  __shared__ __align__(16) double s1t[2];       // [0]=tot(pt) g', [1]=tot(t) g
  __shared__ __align__(16) double s2part[4][264];
  __shared__ __align__(16) double s2f[264];

  const int tid  = threadIdx.x;
  const int lane = tid & 63;          // b
  const int wvid = tid >> 6;          // wave -> rows a = 4*wvid..+3
  const int g    = tid >> 8;          // matvec jj-group
  const int c    = tid & 255;         // matvec column

  // ---- register cache of N column c (fp32, rows 64g..64g+63 of admm ordering) ----
  float nc[64];
#pragma unroll
  for (int k = 0; k < 64; ++k) nc[k] = N32[(64*g + k)*NSP + c];
  const float ncg0 = N32[256*NSP + c];   // g' row (symmetric) -> tot(pt) coupling
  const float ncg1 = N32[257*NSP + c];   // g row -> tot(t) coupling

  // tot-row cache for waves 4/5 (s2[256], s2[257])
  float nr0 = 0.f, nr1 = 0.f, nr2 = 0.f, nr3 = 0.f, nrt0 = 0.f, nrt1 = 0.f;
  if (wvid == 4 || wvid == 5){
    int r = 252 + wvid;   // 256 or 257
    nr0 = N32[r*NSP + lane];       nr1 = N32[r*NSP + lane + 64];
    nr2 = N32[r*NSP + lane + 128]; nr3 = N32[r*NSP + lane + 192];
    nrt0 = N32[r*NSP + 256];       nrt1 = N32[r*NSP + 257];
  }

  // ---- state: fp32 storage, f64 integrators ----
  float pr[4], wr[4], xr[4], vr[4], tq[4];
  double y2a[4], y2b = 0.0;
#pragma unroll
  for (int q = 0; q < 4; ++q){
    int j = (wvid*4 + q)*64 + lane;
    pr[q] = p32[j]; wr[q] = w32[j];
    xr[q] = 0.f; vr[q] = 0.f; tq[q] = 0.f; y2a[q] = 0.0;
  }
  __syncthreads();

  const int rid = tid >> 4, g16 = tid & 15;

  for (int it = 0; it < NITER; ++it){
    // ========== stage 1: y2b fold (f64), t = w*rhs (f64), stage fp32 ==========
    if (it){
      double ybs = 0.0;
#pragma unroll
      for (int s = 0; s < 8; ++s){
        float2 v2 = *(const float2*)&csXl[lane][2*s];
        ybs += (double)v2.x + (double)v2.y;
      }
      y2b += RHO_ * (ybs - 1.0);
    }
    double base = 2.0*RHO_ - y2b;
    double clt = 0.0, clp = 0.0;
#pragma unroll
    for (int q = 0; q < 4; ++q){
      double rhs = SIG_*(double)xr[q] + (double)pr[q] + RHO_*(double)fabsf(vr[q])
                 + base - y2a[q];
      double t = (double)wr[q] * rhs;
      float tf = (float)t;
      tq[q] = tf;
      tb[wvid*4 + q][lane] = make_float2(tf, pr[q]*tf);
      clt += t; clp += (double)pr[q]*t;
    }
    csTP[lane][(wvid + lane) & 15] = make_float2((float)clt, (float)clp);
    __syncthreads();  // B1

    // ========== stage 2: build s1 (fp32) + totals (f64) ==========
    {
      const float4 r0 = *(const float4*)&tb[rid][4*g16];
      const float4 r1 = *(const float4*)&tb[rid][4*g16 + 2];
      float st = (r0.x + r0.z) + (r1.x + r1.z);
      float sp = (r0.y + r0.w) + (r1.y + r1.w);
      st = sum16(st); sp = sum16(sp);
      if (g16 == (rid & 15)){ s1f[192 + rid] = st; s1f[64 + rid] = sp; }
      if (wvid == 0){
        float ct = 0.f, cp = 0.f;
#pragma unroll
        for (int s = 0; s < 8; ++s){
          float4 v4 = *(const float4*)&csTP[lane][2*s];
          ct += v4.x + v4.z; cp += v4.y + v4.w;
        }
        s1f[128 + lane] = ct; s1f[lane] = cp;
        double ctd = (double)ct, cpd = (double)cp;
#pragma unroll
        for (int m2 = 32; m2 >= 1; m2 >>= 1){
          ctd += __shfl_xor(ctd, m2, 64);
          cpd += __shfl_xor(cpd, m2, 64);
        }
        if (lane == 0){ s1t[0] = cpd; s1t[1] = ctd; }
      }
    }
    __syncthreads();  // B2

    // ========== matvec: s2part[g][c] = N[64g..64g+63][c] . s1 (f64 acc) ==========
    {
      double acc = 0.0;
      const float4* s4 = (const float4*)&s1f[64*g];
#pragma unroll
      for (int k2 = 0; k2 < 16; ++k2){
        float4 sv = s4[k2];
        float pa = nc[4*k2]*sv.x + nc[4*k2+1]*sv.y;
        float pb = nc[4*k2+2]*sv.z + nc[4*k2+3]*sv.w;
        acc += (double)pa + (double)pb;
      }
      if (g == 0) acc += (double)ncg0*s1t[0] + (double)ncg1*s1t[1];
      s2part[g][c] = acc;
    }
    __syncthreads();  // B3

    // ========== fold s2 (f64) + tot-rows by waves 4/5 ==========
    if (tid < 256){
      s2f[tid] = (s2part[0][tid] + s2part[1][tid]) + (s2part[2][tid] + s2part[3][tid]);
    } else if (wvid == 4 || wvid == 5){
      int r = 252 + wvid;
      double acc = (double)(nr0*s1f[lane] + nr1*s1f[lane+64])
                 + (double)(nr2*s1f[lane+128] + nr3*s1f[lane+192]);
#pragma unroll
      for (int m2 = 32; m2 >= 1; m2 >>= 1) acc += __shfl_xor(acc, m2, 64);
      if (lane == 0)
        s2f[r] = acc + (double)nrt0*s1t[0] + (double)nrt1*s1t[1];
    }
    __syncthreads();  // B4

    // ========== stage 4: x update (f64), v update, y2a, x col partials ==========
    {
      double a_g  = s2f[257];
      double a_pg = s2f[256];
      double sbE  = s2f[128 + lane];
      double sbPE = s2f[lane];
      double clx = 0.0;
#pragma unroll
      for (int q = 0; q < 4; ++q){
        int arow = wvid*4 + q;
        double corr = a_g + sbE + s2f[192 + arow]
                    + (double)pr[q]*(a_pg + sbPE + s2f[64 + arow]);
        double xn = (double)tq[q] - (double)wr[q]*corr;
        vr[q] = (float)(xn + fmin((double)vr[q], 0.0));
        float xf = (float)xn;
        xr[q] = xf;
        float rsx = wsum64f(xf);
        y2a[q] += RHO_*((double)rsx - 1.0);
        clx += xn;
        if (it == NITER-1) ((float*)tb)[lane*68 + arow] = xf;   // x^T for epilogue
      }
      csXl[lane][(wvid + lane) & 15] = (float)clx;
    }
    __syncthreads();  // B5
  }

  // ========== epilogue: clip + softmax(ALPHA*s, axis=-1) ==========
  const float* xb = (const float*)tb;
#pragma unroll
  for (int q = 0; q < 4; ++q){
    int i = wvid*4 + q;                 // n1 row index
    float val = xb[i*68 + lane];        // x[a=lane][b=i]
    val = fminf(fmaxf(val, 0.f), 1.f);
    float mx = wmax64f(val);
    float e = expf(200.f*(val - mx));
    float sm = wsum64f(e);
    out[i*64 + lane] = e / sm;
  }
}

extern "C" void kernel_launch(void* const* d_in, const int* in_sizes, int n_in,
                              void* d_out, int out_size, void* d_ws, size_t ws_size,
                              hipStream_t stream){
  (void)in_sizes; (void)n_in; (void)out_size; (void)ws_size;
  const float* ft  = (const float*)d_in[0];
  const float* fd  = (const float*)d_in[1];
  const float* iou = (const float*)d_in[2];
  const float* Wm  = (const float*)d_in[3];
  const float* bb  = (const float*)d_in[4];
  char* ws = (char*)d_ws;

  hipMemsetAsync(ws + OFF_BAR, 0, 64, stream);
  hipLaunchKernelGGL(k_prep, dim3(NWG), dim3(256), 0, stream, ft, fd, iou, Wm, bb, ws);

  const float* N32 = (const float*)(ws + OFF_N32);
  const float* p32 = (const float*)(ws + OFF_P32);
  const float* w32 = (const float*)(ws + OFF_W32);
  hipLaunchKernelGGL(k_admm, dim3(1), dim3(1024), 0, stream, N32, p32, w32, (float*)d_out);
}

// Round 6
// 1729.474 us; speedup vs baseline: 2.1011x; 1.1834x over previous
//
#include <hip/hip_runtime.h>
#include <math.h>

#define DD 512
#define NS 258
#define NSP 264
#define NWG 64
#define RHO_ 100.0
#define SIG_ 1e-3
#define NITER 150
#define DELTA0 (3969.0 + SIG_ + RHO_)

// ---------------- workspace byte offsets ----------------
#define OFF_BAR    0u          // unsigned cnt @0, gen @128 (memset to 0 each launch)
#define OFF_E1     512u        // double[64*512]
#define OFF_E2     262656u     // double[64*512]
#define OFF_P      524800u     // double[4096]
#define OFF_W      557568u     // double[4096]
#define OFF_P32    590336u     // float[4096]
#define OFF_W32    606720u     // float[4096]
#define OFF_KSA    623104u     // double[258*264]
#define OFF_KSB    1168000u    // double[258*264]
#define OFF_N32    1712896u    // float[258*264] permuted admm ordering

// permutation: GJ ordering [E',F',g'(128),g(129),E(130..193),F(194..257)]
//          ->  admm ordering [E'(0..63),F'(64..127),E(128..191),F(192..255),g'(256),g(257)]
__device__ __forceinline__ int perm258(int i){
  return (i < 128) ? i : (i == 128) ? 256 : (i == 129) ? 257 : (i - 2);
}

// ---------------- DPP reduction helpers (fp32, VALU pipe) ----------------
template<int CTRL>
__device__ __forceinline__ float dppadd(float v){
  int t = __builtin_amdgcn_mov_dpp(__float_as_int(v), CTRL, 0xF, 0xF, 1);
  return v + __int_as_float(t);
}
template<int CTRL>
__device__ __forceinline__ float dppmax(float v){
  int t = __builtin_amdgcn_mov_dpp(__float_as_int(v), CTRL, 0xF, 0xF, 1);
  return fmaxf(v, __int_as_float(t));
}
__device__ __forceinline__ float sum16(float v){
  v = dppadd<0xB1>(v);   // quad_perm xor1
  v = dppadd<0x4E>(v);   // quad_perm xor2
  v = dppadd<0x124>(v);  // row_ror:4
  v = dppadd<0x128>(v);  // row_ror:8
  return v;
}
__device__ __forceinline__ float wsum64f(float v){
  v = sum16(v);
  v += __shfl_xor(v, 16, 64);
  v += __shfl_xor(v, 32, 64);
  return v;
}
__device__ __forceinline__ float wmax64f(float v){
  v = dppmax<0xB1>(v); v = dppmax<0x4E>(v); v = dppmax<0x124>(v); v = dppmax<0x128>(v);
  v = fmaxf(v, __shfl_xor(v, 16, 64));
  v = fmaxf(v, __shfl_xor(v, 32, 64));
  return v;
}

// ---------------- grid barrier (64 co-resident WGs) ----------------
__device__ __forceinline__ void gsync(unsigned* cnt, unsigned* gen, unsigned& mygen){
  __syncthreads();
  if (threadIdx.x == 0){
    __threadfence();
    unsigned arrived = atomicAdd(cnt, 1u);
    if (arrived == (unsigned)(NWG - 1)){
      atomicExch(cnt, 0u);
      __threadfence();
      atomicAdd(gen, 1u);
    } else {
      while (atomicAdd(gen, 0u) == mygen) { __builtin_amdgcn_s_sleep(8); }
    }
    __threadfence();
  }
  __syncthreads();
  mygen += 1u;
}

// ---- Ksmall index decode: order [E'(0..63), F'(64..127), g'(128), g(129), E(130..193), F(194..257)]
__device__ __forceinline__ void decode_idx(int t, int& cls, int& pr, int& ix){
  if (t < 64)       { cls = 1; pr = 1; ix = t; }
  else if (t < 128) { cls = 2; pr = 1; ix = t - 64; }
  else if (t == 128){ cls = 0; pr = 1; ix = 0; }
  else if (t == 129){ cls = 0; pr = 0; ix = 0; }
  else if (t < 194) { cls = 1; pr = 0; ix = t - 130; }
  else              { cls = 2; pr = 0; ix = t - 194; }
}

// ---- one GJ pivot applied column-partitioned; src -> dstD (f64) or dstF (fp32 permuted)
__device__ void pivot_phase(const double* __restrict__ src, double* __restrict__ dstD,
                            float* __restrict__ dstF, int p0, int m, bool diag,
                            int wg, int tid, double* M, double* temp, double* rcv){
  // 1. pivot-block inverse (redundant per WG) in LDS
  if (diag){
    if (tid < m) M[tid] = 1.0 / src[(size_t)(p0+tid)*NSP + p0 + tid];
    __syncthreads();
  } else {
    for (int idx = tid; idx < m*m; idx += 256)
      M[(idx/m)*67 + (idx%m)] = src[(size_t)(p0 + idx/m)*NSP + p0 + idx%m];
    __syncthreads();
    for (int k = 0; k < m; ++k){
      double pk = 1.0 / M[k*67 + k];
      if (tid < m) rcv[tid] = M[k*67 + tid] * pk;
      else if (tid >= 128 && tid < 128 + m) rcv[66 + tid - 128] = M[(tid-128)*67 + k];
      __syncthreads();
      for (int idx = tid; idx < m*m; idx += 256){
        int i2 = idx/m, j2 = idx%m;
        double nv;
        if (i2 == k)      nv = (j2 == k) ? pk : rcv[j2];
        else if (j2 == k) nv = -rcv[66 + i2] * pk;
        else              nv = M[i2*67 + j2] - rcv[66 + i2] * rcv[j2];
        M[i2*67 + j2] = nv;
      }
      __syncthreads();
    }
  }
  // 2. temp[cidx][k] for owned columns c = wg + 64*cidx
  int ncols = (wg < 2) ? 5 : 4;
  for (int idx = tid; idx < ncols*m; idx += 256){
    int cidx = idx / m, k = idx % m;
    int c = wg + 64*cidx;
    double tv;
    if (c >= p0 && c < p0 + m){
      int kc = c - p0;
      tv = diag ? ((k == kc) ? M[k] : 0.0) : M[k*67 + kc];
    } else if (diag){
      tv = M[k] * src[(size_t)(p0+k)*NSP + c];
    } else {
      double acc = 0;
      for (int l = 0; l < m; ++l) acc += M[k*67 + l] * src[(size_t)(p0+l)*NSP + c];
      tv = acc;
    }
    temp[cidx*68 + k] = tv;
  }
  __syncthreads();
  // 3. all rows for owned columns
  for (int r = tid; r < NS; r += 256){
    if (r >= p0 && r < p0 + m){
      int k = r - p0;
      for (int cidx = 0; cidx < ncols; ++cidx){
        int c = wg + 64*cidx;
        double val = temp[cidx*68 + k];
        if (dstD) dstD[(size_t)r*NSP + c] = val;
        else      dstF[perm258(r)*NSP + perm258(c)] = (float)val;
      }
    } else {
      double acc[5];
      for (int cidx = 0; cidx < ncols; ++cidx){
        int c = wg + 64*cidx;
        acc[cidx] = (c >= p0 && c < p0 + m) ? 0.0 : src[(size_t)r*NSP + c];
      }
      for (int k = 0; k < m; ++k){
        double s = src[(size_t)r*NSP + p0 + k];
        for (int cidx = 0; cidx < ncols; ++cidx) acc[cidx] -= s * temp[cidx*68 + k];
      }
      for (int cidx = 0; cidx < ncols; ++cidx){
        int c = wg + 64*cidx;
        if (dstD) dstD[(size_t)r*NSP + c] = acc[cidx];
        else      dstF[perm258(r)*NSP + perm258(c)] = (float)acc[cidx];
      }
    }
  }
}

// =================== K1: fused prep, 6 grid syncs ===================
__global__ __launch_bounds__(256) void k_prep(const float* __restrict__ ft,
                                              const float* __restrict__ fd,
                                              const float* __restrict__ iou,
                                              const float* __restrict__ Wm,
                                              const float* __restrict__ bb,
                                              char* ws){
  unsigned* cnt = (unsigned*)(ws + OFF_BAR);
  unsigned* gen = (unsigned*)(ws + OFF_BAR + 128);
  double* e1  = (double*)(ws + OFF_E1);
  double* e2  = (double*)(ws + OFF_E2);
  double* p   = (double*)(ws + OFF_P);
  double* w   = (double*)(ws + OFF_W);
  float*  p32 = (float*) (ws + OFF_P32);
  float*  w32 = (float*) (ws + OFF_W32);
  double* KsA = (double*)(ws + OFF_KSA);
  double* KsB = (double*)(ws + OFF_KSB);
  float*  N32 = (float*) (ws + OFF_N32);

  __shared__ double SH[4928];   // 39.4 KB, aliased per phase

  int tid = threadIdx.x;
  int wg  = blockIdx.x;
  unsigned mygen = 0u;

  // ---------- Phase 1: features (row i AND col i per WG, no barrier) ----------
  {
    float* ftR = (float*)SH;          // 512
    float* fdR = ftR + 512;           // 512
    float* u1R = fdR + 512;           // 512
    float* u2R = u1R + 512;           // 512
    double* m0r = SH + 1024;          // 64
    double* m0c = m0r + 64;           // 64
    double* red = m0c + 64;           // 256
    double* sca = red + 256;          // 8
    int i = wg;
    for (int k = tid; k < DD; k += 256){ ftR[k] = ft[i*DD + k]; fdR[k] = fd[i*DD + k]; }
    __syncthreads();
    // norms of ft_i, fd_i
    {
      double nf = 0, nd = 0;
      for (int k = tid; k < DD; k += 256){
        nf += (double)ftR[k]*ftR[k]; nd += (double)fdR[k]*fdR[k];
      }
      red[tid] = nf; __syncthreads();
      for (int o = 128; o; o >>= 1){ if (tid < o) red[tid] += red[tid+o]; __syncthreads(); }
      if (tid == 0) sca[0] = red[0];
      __syncthreads();
      red[tid] = nd; __syncthreads();
      for (int o = 128; o; o >>= 1){ if (tid < o) red[tid] += red[tid+o]; __syncthreads(); }
      if (tid == 0) sca[1] = red[0];
      __syncthreads();
    }
    // Mp0 row i and column i
    {
      int j = tid >> 2, sub = tid & 3, k0 = sub*128;
      double ar = 0, ac = 0;
      for (int k = k0; k < k0 + 128; ++k){
        ar += (double)ftR[k] * (double)fd[j*DD + k];
        ac += (double)fdR[k] * (double)ft[j*DD + k];
      }
      red[tid] = ar; __syncthreads();
      if (sub == 0) m0r[j] = red[tid]+red[tid+1]+red[tid+2]+red[tid+3] + (double)iou[i*64 + j];
      __syncthreads();
      red[tid] = ac; __syncthreads();
      if (sub == 0) m0c[j] = red[tid]+red[tid+1]+red[tid+2]+red[tid+3] + (double)iou[j*64 + i];
      __syncthreads();
    }
    // m1 = Mp0row @ fd ; m2 = Mp0col @ ft ; lambdas ; u rows
    double mv1[2], mv2[2];
    {
      double n1 = 0, n2 = 0;
      for (int h = 0; h < 2; ++h){
        int c = tid + h*256;
        double a1 = 0, a2 = 0;
        for (int a = 0; a < 64; ++a){
          a1 += m0r[a] * (double)fd[a*DD + c];
          a2 += m0c[a] * (double)ft[a*DD + c];
        }
        mv1[h] = a1; mv2[h] = a2; n1 += a1*a1; n2 += a2*a2;
      }
      red[tid] = n1; __syncthreads();
      for (int o = 128; o; o >>= 1){ if (tid < o) red[tid] += red[tid+o]; __syncthreads(); }
      if (tid == 0) sca[2] = sqrt(sca[0] / red[0]);
      __syncthreads();
      red[tid] = n2; __syncthreads();
      for (int o = 128; o; o >>= 1){ if (tid < o) red[tid] += red[tid+o]; __syncthreads(); }
      if (tid == 0) sca[3] = sqrt(sca[1] / red[0]);
      __syncthreads();
      double l1 = sca[2], l2 = sca[3];
      for (int h = 0; h < 2; ++h){
        int c = tid + h*256;
        u1R[c] = (float)((double)ftR[c] + l1*mv1[h]);
        u2R[c] = (float)((double)fdR[c] + l2*mv2[h]);
      }
      __syncthreads();
    }
    // egemm both rows with one Wm stream
    {
      double v1[2], v2[2], q1 = 0, q2 = 0;
      for (int h = 0; h < 2; ++h){
        int c = tid + h*256;
        const float* wrp = Wm + (size_t)c*DD;
        double a1 = (double)bb[c], a2 = a1;
        for (int k = 0; k < DD; k += 4){
          float4 wq  = *(const float4*)(wrp + k);
          float4 uq1 = *(const float4*)(u1R + k);
          float4 uq2 = *(const float4*)(u2R + k);
          a1 += (double)uq1.x*wq.x + (double)uq1.y*wq.y + (double)uq1.z*wq.z + (double)uq1.w*wq.w;
          a2 += (double)uq2.x*wq.x + (double)uq2.y*wq.y + (double)uq2.z*wq.z + (double)uq2.w*wq.w;
        }
        a1 = fmax(a1, 0.0); a2 = fmax(a2, 0.0);
        v1[h] = a1; v2[h] = a2; q1 += a1*a1; q2 += a2*a2;
      }
      red[tid] = q1; __syncthreads();
      for (int o = 128; o; o >>= 1){ if (tid < o) red[tid] += red[tid+o]; __syncthreads(); }
      if (tid == 0) sca[4] = 1.0 / fmax(sqrt(red[0]), 1e-12);
      __syncthreads();
      red[tid] = q2; __syncthreads();
      for (int o = 128; o; o >>= 1){ if (tid < o) red[tid] += red[tid+o]; __syncthreads(); }
      if (tid == 0) sca[5] = 1.0 / fmax(sqrt(red[0]), 1e-12);
      __syncthreads();
      double i1 = sca[4], i2 = sca[5];
      for (int h = 0; h < 2; ++h){
        int c = tid + h*256;
        e1[(size_t)i*DD + c] = v1[h]*i1;
        e2[(size_t)i*DD + c] = v2[h]*i2;
      }
    }
  }
  gsync(cnt, gen, mygen);   // G1

  // ---------- Phase 2: p[a*64+b] = e1[b].e2[a]; w = 1/(D0-p) ----------
  {
    double* e2R = SH;          // 512
    double* red = SH + 512;    // 256
    int a = wg;
    for (int k = tid; k < DD; k += 256) e2R[k] = e2[(size_t)a*DD + k];
    __syncthreads();
    int b = tid >> 2, sub = tid & 3, k0 = sub*128;
    double acc = 0;
    for (int k = k0; k < k0 + 128; ++k) acc += e1[(size_t)b*DD + k] * e2R[k];
    red[tid] = acc; __syncthreads();
    if (sub == 0){
      double pv = red[tid]+red[tid+1]+red[tid+2]+red[tid+3];
      double wv = 1.0 / (DELTA0 - pv);
      int j = a*64 + b;
      p[j] = pv; w[j] = wv; p32[j] = (float)pv; w32[j] = (float)wv;
    }
  }
  gsync(cnt, gen, mygen);   // G2

  // ---------- Phase 3: sums (redundant) + assemble KsA ----------
  {
    double* sumsL = SH;          // 392
    double* red3  = SH + 392;    // 768
    int a = tid >> 2, sub = tid & 3;
    double r0 = 0, r1 = 0, r2 = 0;
    for (int b = sub*16; b < sub*16 + 16; ++b){
      double wv = w[a*64 + b], pv = p[a*64 + b];
      r0 += wv; r1 += wv*pv; r2 += wv*pv*pv;
    }
    red3[tid*3] = r0; red3[tid*3+1] = r1; red3[tid*3+2] = r2;
    __syncthreads();
    if (tid < 64){
      double t0 = 0, t1 = 0, t2 = 0;
      for (int s = 0; s < 4; ++s){
        t0 += red3[(tid*4+s)*3]; t1 += red3[(tid*4+s)*3+1]; t2 += red3[(tid*4+s)*3+2];
      }
      sumsL[200 + tid] = t0; sumsL[200 + 64 + tid] = t1; sumsL[200 + 128 + tid] = t2;
    }
    __syncthreads();
    int b2 = tid >> 2;
    double c0 = 0, c1 = 0, c2 = 0;
    for (int a2 = sub*16; a2 < sub*16 + 16; ++a2){
      double wv = w[a2*64 + b2], pv = p[a2*64 + b2];
      c0 += wv; c1 += wv*pv; c2 += wv*pv*pv;
    }
    __syncthreads();
    red3[tid*3] = c0; red3[tid*3+1] = c1; red3[tid*3+2] = c2;
    __syncthreads();
    if (tid < 64){
      double t0 = 0, t1 = 0, t2 = 0;
      for (int s = 0; s < 4; ++s){
        t0 += red3[(tid*4+s)*3]; t1 += red3[(tid*4+s)*3+1]; t2 += red3[(tid*4+s)*3+2];
      }
      sumsL[8 + tid] = t0; sumsL[8 + 64 + tid] = t1; sumsL[8 + 128 + tid] = t2;
    }
    __syncthreads();
    if (tid == 0){
      double t0 = 0, t1 = 0, t2 = 0;
      for (int a3 = 0; a3 < 64; ++a3){
        t0 += sumsL[200 + a3]; t1 += sumsL[200 + 64 + a3]; t2 += sumsL[200 + 128 + a3];
      }
      sumsL[0] = t0; sumsL[1] = t1; sumsL[2] = t2;
    }
    __syncthreads();
    for (int idx = wg*256 + tid; idx < NS*NS; idx += NWG*256){
      int r = idx / NS, c = idx % NS;
      int cr, prr, ir, cc, prc, ic;
      decode_idx(r, cr, prr, ir);
      decode_idx(c, cc, prc, ic);
      int m = prr + prc;
      double tval;
      if (cr == 0 && cc == 0)      tval = sumsL[m];
      else if (cr == 0 && cc == 1) tval = sumsL[8 + m*64 + ic];
      else if (cr == 1 && cc == 0) tval = sumsL[8 + m*64 + ir];
      else if (cr == 0 && cc == 2) tval = sumsL[200 + m*64 + ic];
      else if (cr == 2 && cc == 0) tval = sumsL[200 + m*64 + ir];
      else if (cr == 1 && cc == 1) tval = (ir == ic) ? sumsL[8 + m*64 + ir] : 0.0;
      else if (cr == 2 && cc == 2) tval = (ir == ic) ? sumsL[200 + m*64 + ir] : 0.0;
      else if (cr == 1 && cc == 2){
        double wv = w[ic*64 + ir], pv = p[ic*64 + ir];
        tval = (m == 0) ? wv : (m == 1) ? wv*pv : wv*pv*pv;
      } else {
        double wv = w[ir*64 + ic], pv = p[ir*64 + ic];
        tval = (m == 0) ? wv : (m == 1) ? wv*pv : wv*pv*pv;
      }
      double mv2 = 0.0;
      if (cr == 0 && cc == 0 && prr != prc) mv2 = -2.0;
      if (cr != 0 && cr == cc && ir == ic){
        if (prr != prc) mv2 = 2.0;
        else if (prr == 1) mv2 = -4.0 * RHO_;
      }
      KsA[(size_t)r*NSP + c] = tval + mv2;
    }
  }
  gsync(cnt, gen, mygen);   // G3

  // ---------- Phases 4-7: GJ pivots, one gsync each, ping-pong ----------
  {
    double* M    = SH;           // up to 66*67 = 4422
    double* temp = SH + 4422;    // 5*68 = 340
    double* rcv  = SH + 4762;    // 132
    pivot_phase(KsA, KsB, nullptr, 0,   64, true,  wg, tid, M, temp, rcv);
    gsync(cnt, gen, mygen);   // G4
    pivot_phase(KsB, KsA, nullptr, 64,  66, false, wg, tid, M, temp, rcv);
    gsync(cnt, gen, mygen);   // G5
    pivot_phase(KsA, KsB, nullptr, 130, 64, false, wg, tid, M, temp, rcv);
    gsync(cnt, gen, mygen);   // G6
    pivot_phase(KsB, nullptr, N32, 194, 64, false, wg, tid, M, temp, rcv);
  }
}

// =================== K2: persistent single-WG ADMM + softmax ===================
// s1/s2 admm ordering: [0..63]=cs(pt) E', [64..127]=rs(pt) F', [128..191]=cs(t) E,
// [192..255]=rs(t) F, s1g2[0]=tot(pt) g', s1g2[1]=tot(t) g
__global__ __launch_bounds__(1024, 4) void k_admm(const float* __restrict__ N32,
                                                  const float* __restrict__ p32,
                                                  const float* __restrict__ w32,
                                                  float* __restrict__ out){
  __shared__ float2 tb[64][66];       // (t, p*t) staging; reused for x^T at end
  __shared__ float2 csTP[64][18];     // col-sum partials (t, p*t) per (b, wave)
  __shared__ float  csXl[64][18];     // col-sum partials of x per (b, wave)
  __shared__ __align__(16) float  s1f[264];
  __shared__ float  s1g2[2];          // [0]=tot(pt), [1]=tot(t)
  __shared__ float  s2g[2];           // matvec outputs rows 256 (g'), 257 (g)
  __shared__ __align__(16) double s2part[4][264];

  const int tid  = threadIdx.x;
  const int lane = tid & 63;          // b
  const int wvid = tid >> 6;          // wave -> rows a = 4*wvid..+3
  const int g    = tid >> 8;          // matvec jj-group
  const int c    = tid & 255;         // matvec column

  // ---- register cache of N column c (fp32, rows 64g..64g+63 of admm ordering) ----
  float nc[64];
#pragma unroll
  for (int k = 0; k < 64; ++k) nc[k] = N32[(64*g + k)*NSP + c];
  const float ncg0 = N32[256*NSP + c];
  const float ncg1 = N32[257*NSP + c];

  // tot-row cache for waves 4/5
  float nr0 = 0.f, nr1 = 0.f, nr2 = 0.f, nr3 = 0.f, nrt0 = 0.f, nrt1 = 0.f;
  if (wvid == 4 || wvid == 5){
    int r = 252 + wvid;   // 256 or 257
    nr0 = N32[r*NSP + lane];       nr1 = N32[r*NSP + lane + 64];
    nr2 = N32[r*NSP + lane + 128]; nr3 = N32[r*NSP + lane + 192];
    nrt0 = N32[r*NSP + 256];       nrt1 = N32[r*NSP + 257];
  }

  // ---- state: fp32 storage, f64 integrators ----
  float pr[4], wr[4], xr[4], vr[4], tq[4];
  double y2a[4], y2b = 0.0;
#pragma unroll
  for (int q = 0; q < 4; ++q){
    int j = (wvid*4 + q)*64 + lane;
    pr[q] = p32[j]; wr[q] = w32[j];
    xr[q] = 0.f; vr[q] = 0.f; tq[q] = 0.f; y2a[q] = 0.0;
  }
  __syncthreads();

  const int rid = tid >> 4, g16 = tid & 15;

  for (int it = 0; it < NITER; ++it){
    // ========== stage 1: y2b fold (f64), t = w*rhs (f64), stage fp32 ==========
    if (it){
      double ybs = 0.0;
#pragma unroll
      for (int s = 0; s < 8; ++s){
        float2 v2 = *(const float2*)&csXl[lane][2*s];
        ybs += (double)v2.x + (double)v2.y;
      }
      y2b += RHO_ * (ybs - 1.0);
    }
    double base = 2.0*RHO_ - y2b;
    double clt = 0.0, clp = 0.0;
#pragma unroll
    for (int q = 0; q < 4; ++q){
      double rhs = SIG_*(double)xr[q] + (double)pr[q] + RHO_*(double)fabsf(vr[q])
                 + base - y2a[q];
      double t = (double)wr[q] * rhs;
      float tf = (float)t;
      tq[q] = tf;
      tb[wvid*4 + q][lane] = make_float2(tf, pr[q]*tf);
      clt += t; clp += (double)pr[q]*t;
    }
    csTP[lane][(wvid + lane) & 15] = make_float2((float)clt, (float)clp);
    __syncthreads();  // B1

    // ========== stage 2: build s1 (fp32) + totals (fp32 DPP) ==========
    {
      const float4 r0 = *(const float4*)&tb[rid][4*g16];
      const float4 r1 = *(const float4*)&tb[rid][4*g16 + 2];
      float st = (r0.x + r0.z) + (r1.x + r1.z);
      float sp = (r0.y + r0.w) + (r1.y + r1.w);
      st = sum16(st); sp = sum16(sp);
      if (g16 == (rid & 15)){ s1f[192 + rid] = st; s1f[64 + rid] = sp; }
      if (wvid == 0){
        float ct = 0.f, cp = 0.f;
#pragma unroll
        for (int s = 0; s < 8; ++s){
          float4 v4 = *(const float4*)&csTP[lane][2*s];
          ct += v4.x + v4.z; cp += v4.y + v4.w;
        }
        s1f[128 + lane] = ct; s1f[lane] = cp;
        float tt = wsum64f(ct);
        float tp = wsum64f(cp);
        if (lane == 0){ s1g2[1] = tt; s1g2[0] = tp; }
      }
    }
    __syncthreads();  // B2

    // ========== matvec: s2part[g][c] = N[64g..64g+63][c] . s1 (f64 acc) ==========
    {
      double acc = 0.0;
      const float4* s4 = (const float4*)&s1f[64*g];
#pragma unroll
      for (int k2 = 0; k2 < 16; ++k2){
        float4 sv = s4[k2];
        float pa = nc[4*k2]*sv.x + nc[4*k2+1]*sv.y;
        float pb = nc[4*k2+2]*sv.z + nc[4*k2+3]*sv.w;
        acc += (double)pa + (double)pb;
      }
      if (g == 0) acc += (double)(ncg0*s1g2[0]) + (double)(ncg1*s1g2[1]);
      s2part[g][c] = acc;
      if (wvid == 4 || wvid == 5){
        float a32 = nr0*s1f[lane] + nr1*s1f[lane+64]
                  + nr2*s1f[lane+128] + nr3*s1f[lane+192];
        a32 = wsum64f(a32);
        if (lane == 0) s2g[wvid - 4] = a32 + nrt0*s1g2[0] + nrt1*s1g2[1];
      }
    }
    __syncthreads();  // B3

    // ========== stage 4: x update (f64), v update, y2a, x col partials ==========
    {
      double a_pg = (double)s2g[0];
      double a_g  = (double)s2g[1];
      double sbE  = s2part[0][128+lane] + s2part[1][128+lane]
                  + s2part[2][128+lane] + s2part[3][128+lane];
      double sbPE = s2part[0][lane] + s2part[1][lane]
                  + s2part[2][lane] + s2part[3][lane];
      double clx = 0.0;
#pragma unroll
      for (int q = 0; q < 4; ++q){
        int arow = wvid*4 + q;
        double sF  = s2part[0][192+arow] + s2part[1][192+arow]
                   + s2part[2][192+arow] + s2part[3][192+arow];
        double sPF = s2part[0][64+arow] + s2part[1][64+arow]
                   + s2part[2][64+arow] + s2part[3][64+arow];
        double corr = a_g + sbE + sF + (double)pr[q]*(a_pg + sbPE + sPF);
        double xn = (double)tq[q] - (double)wr[q]*corr;
        vr[q] = (float)(xn + fmin((double)vr[q], 0.0));
        float xf = (float)xn;
        xr[q] = xf;
        float rsx = wsum64f(xf);
        y2a[q] += RHO_*((double)rsx - 1.0);
        clx += xn;
        if (it == NITER-1) ((float*)tb)[lane*68 + arow] = xf;   // x^T for epilogue
      }
      csXl[lane][(wvid + lane) & 15] = (float)clx;
    }
    __syncthreads();  // B4
  }

  // ========== epilogue: clip + softmax(ALPHA*s, axis=-1) ==========
  const float* xb = (const float*)tb;
#pragma unroll
  for (int q = 0; q < 4; ++q){
    int i = wvid*4 + q;                 // n1 row index
    float val = xb[i*68 + lane];        // x[a=lane][b=i]
    val = fminf(fmaxf(val, 0.f), 1.f);
    float mx = wmax64f(val);
    float e = expf(200.f*(val - mx));
    float sm = wsum64f(e);
    out[i*64 + lane] = e / sm;
  }
}

extern "C" void kernel_launch(void* const* d_in, const int* in_sizes, int n_in,
                              void* d_out, int out_size, void* d_ws, size_t ws_size,
                              hipStream_t stream){
  (void)in_sizes; (void)n_in; (void)out_size; (void)ws_size;
  const float* ft  = (const float*)d_in[0];
  const float* fd  = (const float*)d_in[1];
  const float* iou = (const float*)d_in[2];
  const float* Wm  = (const float*)d_in[3];
  const float* bb  = (const float*)d_in[4];
  char* ws = (char*)d_ws;

  hipMemsetAsync(ws + OFF_BAR, 0, 512, stream);
  hipLaunchKernelGGL(k_prep, dim3(NWG), dim3(256), 0, stream, ft, fd, iou, Wm, bb, ws);

  const float* N32 = (const float*)(ws + OFF_N32);
  const float* p32 = (const float*)(ws + OFF_P32);
  const float* w32 = (const float*)(ws + OFF_W32);
  hipLaunchKernelGGL(k_admm, dim3(1), dim3(1024), 0, stream, N32, p32, w32, (float*)d_out);
}

// Round 7
// 1399.329 us; speedup vs baseline: 2.5968x; 1.2359x over previous
//
#include <hip/hip_runtime.h>
#include <math.h>

#define DD 512
#define NS 258
#define NSP 264
#define NWG 64
#define RHO_ 100.0
#define SIG_ 1e-3
#define NITER 150
#define DELTA0 (3969.0 + SIG_ + RHO_)

// ---------------- workspace byte offsets ----------------
#define OFF_BAR    0u          // unsigned cnt @0, gen @128 (memset to 0 each launch)
#define OFF_E1     512u        // double[64*512]
#define OFF_E2     262656u     // double[64*512]
#define OFF_P      524800u     // double[4096]
#define OFF_W      557568u     // double[4096]
#define OFF_P32    590336u     // float[4096]
#define OFF_W32    606720u     // float[4096]
#define OFF_KSA    623104u     // double[258*264]
#define OFF_KSB    1168000u    // double[258*264]
#define OFF_N32    1712896u    // float[258*264] permuted admm ordering

// permutation: GJ ordering [E',F',g'(128),g(129),E(130..193),F(194..257)]
//          ->  admm ordering [E'(0..63),F'(64..127),E(128..191),F(192..255),g'(256),g(257)]
__device__ __forceinline__ int perm258(int i){
  return (i < 128) ? i : (i == 128) ? 256 : (i == 129) ? 257 : (i - 2);
}

// ---------------- DPP reduction helpers (fp32, VALU pipe) ----------------
template<int CTRL>
__device__ __forceinline__ float dppadd(float v){
  int t = __builtin_amdgcn_mov_dpp(__float_as_int(v), CTRL, 0xF, 0xF, 1);
  return v + __int_as_float(t);
}
template<int CTRL>
__device__ __forceinline__ float dppmax(float v){
  int t = __builtin_amdgcn_mov_dpp(__float_as_int(v), CTRL, 0xF, 0xF, 1);
  return fmaxf(v, __int_as_float(t));
}
__device__ __forceinline__ float sum16(float v){
  v = dppadd<0xB1>(v);   // quad_perm xor1
  v = dppadd<0x4E>(v);   // quad_perm xor2
  v = dppadd<0x124>(v);  // row_ror:4
  v = dppadd<0x128>(v);  // row_ror:8
  return v;
}
__device__ __forceinline__ float wsum64f(float v){
  v = sum16(v);
  v += __shfl_xor(v, 16, 64);
  v += __shfl_xor(v, 32, 64);
  return v;
}
__device__ __forceinline__ float wmax64f(float v){
  v = dppmax<0xB1>(v); v = dppmax<0x4E>(v); v = dppmax<0x124>(v); v = dppmax<0x128>(v);
  v = fmaxf(v, __shfl_xor(v, 16, 64));
  v = fmaxf(v, __shfl_xor(v, 32, 64));
  return v;
}

// ---------------- grid barrier (64 co-resident WGs) ----------------
__device__ __forceinline__ void gsync(unsigned* cnt, unsigned* gen, unsigned& mygen){
  __syncthreads();
  if (threadIdx.x == 0){
    __threadfence();
    unsigned arrived = atomicAdd(cnt, 1u);
    if (arrived == (unsigned)(NWG - 1)){
      atomicExch(cnt, 0u);
      __threadfence();
      atomicAdd(gen, 1u);
    } else {
      while (atomicAdd(gen, 0u) == mygen) { __builtin_amdgcn_s_sleep(32); }
    }
    __threadfence();
  }
  __syncthreads();
  mygen += 1u;
}

// ---- Ksmall index decode: order [E'(0..63), F'(64..127), g'(128), g(129), E(130..193), F(194..257)]
__device__ __forceinline__ void decode_idx(int t, int& cls, int& pr, int& ix){
  if (t < 64)       { cls = 1; pr = 1; ix = t; }
  else if (t < 128) { cls = 2; pr = 1; ix = t - 64; }
  else if (t == 128){ cls = 0; pr = 1; ix = 0; }
  else if (t == 129){ cls = 0; pr = 0; ix = 0; }
  else if (t < 194) { cls = 1; pr = 0; ix = t - 130; }
  else              { cls = 2; pr = 0; ix = t - 194; }
}

// ---- closed-form K_small(r,c) (identical logic to the old assembly loop) ----
__device__ double ksval(int r, int c, const double* __restrict__ p,
                        const double* __restrict__ w, const double* sumsL){
  int cr, prr, ir, cc, prc, ic;
  decode_idx(r, cr, prr, ir);
  decode_idx(c, cc, prc, ic);
  int m = prr + prc;
  double tval;
  if (cr == 0 && cc == 0)      tval = sumsL[m];
  else if (cr == 0 && cc == 1) tval = sumsL[8 + m*64 + ic];
  else if (cr == 1 && cc == 0) tval = sumsL[8 + m*64 + ir];
  else if (cr == 0 && cc == 2) tval = sumsL[200 + m*64 + ic];
  else if (cr == 2 && cc == 0) tval = sumsL[200 + m*64 + ir];
  else if (cr == 1 && cc == 1) tval = (ir == ic) ? sumsL[8 + m*64 + ir] : 0.0;
  else if (cr == 2 && cc == 2) tval = (ir == ic) ? sumsL[200 + m*64 + ir] : 0.0;
  else if (cr == 1 && cc == 2){
    double wv = w[ic*64 + ir], pv = p[ic*64 + ir];
    tval = (m == 0) ? wv : (m == 1) ? wv*pv : wv*pv*pv;
  } else {
    double wv = w[ir*64 + ic], pv = p[ir*64 + ic];
    tval = (m == 0) ? wv : (m == 1) ? wv*pv : wv*pv*pv;
  }
  double mv2 = 0.0;
  if (cr == 0 && cc == 0 && prr != prc) mv2 = -2.0;
  if (cr != 0 && cr == cc && ir == ic){
    if (prr != prc) mv2 = 2.0;
    else if (prr == 1) mv2 = -4.0 * RHO_;
  }
  return tval + mv2;
}

// ---- one GJ pivot applied column-partitioned; src -> dstD (f64) or dstF (fp32 permuted)
__device__ void pivot_phase(const double* __restrict__ src, double* __restrict__ dstD,
                            float* __restrict__ dstF, int p0, int m,
                            int wg, int tid, double* M, double* temp, double* rcv){
  // 1. pivot-block inverse (redundant per WG) in LDS
  for (int idx = tid; idx < m*m; idx += 256)
    M[(idx/m)*67 + (idx%m)] = src[(size_t)(p0 + idx/m)*NSP + p0 + idx%m];
  __syncthreads();
  for (int k = 0; k < m; ++k){
    double pk = 1.0 / M[k*67 + k];
    if (tid < m) rcv[tid] = M[k*67 + tid] * pk;
    else if (tid >= 128 && tid < 128 + m) rcv[66 + tid - 128] = M[(tid-128)*67 + k];
    __syncthreads();
    for (int idx = tid; idx < m*m; idx += 256){
      int i2 = idx/m, j2 = idx%m;
      double nv;
      if (i2 == k)      nv = (j2 == k) ? pk : rcv[j2];
      else if (j2 == k) nv = -rcv[66 + i2] * pk;
      else              nv = M[i2*67 + j2] - rcv[66 + i2] * rcv[j2];
      M[i2*67 + j2] = nv;
    }
    __syncthreads();
  }
  // 2. temp[cidx][k] for owned columns c = wg + 64*cidx
  int ncols = (wg < 2) ? 5 : 4;
  for (int idx = tid; idx < ncols*m; idx += 256){
    int cidx = idx / m, k = idx % m;
    int c = wg + 64*cidx;
    double tv;
    if (c >= p0 && c < p0 + m){
      tv = M[k*67 + (c - p0)];
    } else {
      double acc = 0;
      for (int l = 0; l < m; ++l) acc += M[k*67 + l] * src[(size_t)(p0+l)*NSP + c];
      tv = acc;
    }
    temp[cidx*68 + k] = tv;
  }
  __syncthreads();
  // 3. all rows for owned columns
  for (int r = tid; r < NS; r += 256){
    if (r >= p0 && r < p0 + m){
      int k = r - p0;
      for (int cidx = 0; cidx < ncols; ++cidx){
        int c = wg + 64*cidx;
        double val = temp[cidx*68 + k];
        if (dstD) dstD[(size_t)r*NSP + c] = val;
        else      dstF[perm258(r)*NSP + perm258(c)] = (float)val;
      }
    } else {
      double acc[5];
      for (int cidx = 0; cidx < ncols; ++cidx){
        int c = wg + 64*cidx;
        acc[cidx] = (c >= p0 && c < p0 + m) ? 0.0 : src[(size_t)r*NSP + c];
      }
      for (int k = 0; k < m; ++k){
        double s = src[(size_t)r*NSP + p0 + k];
        for (int cidx = 0; cidx < ncols; ++cidx) acc[cidx] -= s * temp[cidx*68 + k];
      }
      for (int cidx = 0; cidx < ncols; ++cidx){
        int c = wg + 64*cidx;
        if (dstD) dstD[(size_t)r*NSP + c] = acc[cidx];
        else      dstF[perm258(r)*NSP + perm258(c)] = (float)acc[cidx];
      }
    }
  }
}

// =================== K1: fused prep, 5 grid syncs ===================
__global__ __launch_bounds__(256) void k_prep(const float* __restrict__ ft,
                                              const float* __restrict__ fd,
                                              const float* __restrict__ iou,
                                              const float* __restrict__ Wm,
                                              const float* __restrict__ bb,
                                              char* ws){
  unsigned* cnt = (unsigned*)(ws + OFF_BAR);
  unsigned* gen = (unsigned*)(ws + OFF_BAR + 128);
  double* e1  = (double*)(ws + OFF_E1);
  double* e2  = (double*)(ws + OFF_E2);
  double* p   = (double*)(ws + OFF_P);
  double* w   = (double*)(ws + OFF_W);
  float*  p32 = (float*) (ws + OFF_P32);
  float*  w32 = (float*) (ws + OFF_W32);
  double* KsA = (double*)(ws + OFF_KSA);
  double* KsB = (double*)(ws + OFF_KSB);
  float*  N32 = (float*) (ws + OFF_N32);

  __shared__ double SH[4928];   // 39.4 KB, aliased per phase

  int tid = threadIdx.x;
  int wg  = blockIdx.x;
  unsigned mygen = 0u;

  // ---------- Phase 1: features (row i AND col i per WG, no barrier) ----------
  {
    float* ftR = (float*)SH;          // 512
    float* fdR = ftR + 512;           // 512
    float* u1R = fdR + 512;           // 512
    float* u2R = u1R + 512;           // 512
    double* m0r = SH + 1024;          // 64
    double* m0c = m0r + 64;           // 64
    double* red = m0c + 64;           // 256
    double* sca = red + 256;          // 8
    int i = wg;
    for (int k = tid; k < DD; k += 256){ ftR[k] = ft[i*DD + k]; fdR[k] = fd[i*DD + k]; }
    __syncthreads();
    {
      double nf = 0, nd = 0;
      for (int k = tid; k < DD; k += 256){
        nf += (double)ftR[k]*ftR[k]; nd += (double)fdR[k]*fdR[k];
      }
      red[tid] = nf; __syncthreads();
      for (int o = 128; o; o >>= 1){ if (tid < o) red[tid] += red[tid+o]; __syncthreads(); }
      if (tid == 0) sca[0] = red[0];
      __syncthreads();
      red[tid] = nd; __syncthreads();
      for (int o = 128; o; o >>= 1){ if (tid < o) red[tid] += red[tid+o]; __syncthreads(); }
      if (tid == 0) sca[1] = red[0];
      __syncthreads();
    }
    {
      int j = tid >> 2, sub = tid & 3, k0 = sub*128;
      double ar = 0, ac = 0;
      for (int k = k0; k < k0 + 128; ++k){
        ar += (double)ftR[k] * (double)fd[j*DD + k];
        ac += (double)fdR[k] * (double)ft[j*DD + k];
      }
      red[tid] = ar; __syncthreads();
      if (sub == 0) m0r[j] = red[tid]+red[tid+1]+red[tid+2]+red[tid+3] + (double)iou[i*64 + j];
      __syncthreads();
      red[tid] = ac; __syncthreads();
      if (sub == 0) m0c[j] = red[tid]+red[tid+1]+red[tid+2]+red[tid+3] + (double)iou[j*64 + i];
      __syncthreads();
    }
    double mv1[2], mv2[2];
    {
      double n1 = 0, n2 = 0;
      for (int h = 0; h < 2; ++h){
        int c = tid + h*256;
        double a1 = 0, a2 = 0;
        for (int a = 0; a < 64; ++a){
          a1 += m0r[a] * (double)fd[a*DD + c];
          a2 += m0c[a] * (double)ft[a*DD + c];
        }
        mv1[h] = a1; mv2[h] = a2; n1 += a1*a1; n2 += a2*a2;
      }
      red[tid] = n1; __syncthreads();
      for (int o = 128; o; o >>= 1){ if (tid < o) red[tid] += red[tid+o]; __syncthreads(); }
      if (tid == 0) sca[2] = sqrt(sca[0] / red[0]);
      __syncthreads();
      red[tid] = n2; __syncthreads();
      for (int o = 128; o; o >>= 1){ if (tid < o) red[tid] += red[tid+o]; __syncthreads(); }
      if (tid == 0) sca[3] = sqrt(sca[1] / red[0]);
      __syncthreads();
      double l1 = sca[2], l2 = sca[3];
      for (int h = 0; h < 2; ++h){
        int c = tid + h*256;
        u1R[c] = (float)((double)ftR[c] + l1*mv1[h]);
        u2R[c] = (float)((double)fdR[c] + l2*mv2[h]);
      }
      __syncthreads();
    }
    {
      double v1[2], v2[2], q1 = 0, q2 = 0;
      for (int h = 0; h < 2; ++h){
        int c = tid + h*256;
        const float* wrp = Wm + (size_t)c*DD;
        double a1 = (double)bb[c], a2 = a1;
        for (int k = 0; k < DD; k += 4){
          float4 wq  = *(const float4*)(wrp + k);
          float4 uq1 = *(const float4*)(u1R + k);
          float4 uq2 = *(const float4*)(u2R + k);
          a1 += (double)uq1.x*wq.x + (double)uq1.y*wq.y + (double)uq1.z*wq.z + (double)uq1.w*wq.w;
          a2 += (double)uq2.x*wq.x + (double)uq2.y*wq.y + (double)uq2.z*wq.z + (double)uq2.w*wq.w;
        }
        a1 = fmax(a1, 0.0); a2 = fmax(a2, 0.0);
        v1[h] = a1; v2[h] = a2; q1 += a1*a1; q2 += a2*a2;
      }
      red[tid] = q1; __syncthreads();
      for (int o = 128; o; o >>= 1){ if (tid < o) red[tid] += red[tid+o]; __syncthreads(); }
      if (tid == 0) sca[4] = 1.0 / fmax(sqrt(red[0]), 1e-12);
      __syncthreads();
      red[tid] = q2; __syncthreads();
      for (int o = 128; o; o >>= 1){ if (tid < o) red[tid] += red[tid+o]; __syncthreads(); }
      if (tid == 0) sca[5] = 1.0 / fmax(sqrt(red[0]), 1e-12);
      __syncthreads();
      double i1 = sca[4], i2 = sca[5];
      for (int h = 0; h < 2; ++h){
        int c = tid + h*256;
        e1[(size_t)i*DD + c] = v1[h]*i1;
        e2[(size_t)i*DD + c] = v2[h]*i2;
      }
    }
  }
  gsync(cnt, gen, mygen);   // G1

  // ---------- Phase 2: p[a*64+b] = e1[b].e2[a]; w = 1/(D0-p) ----------
  {
    double* e2R = SH;          // 512
    double* red = SH + 512;    // 256
    int a = wg;
    for (int k = tid; k < DD; k += 256) e2R[k] = e2[(size_t)a*DD + k];
    __syncthreads();
    int b = tid >> 2, sub = tid & 3, k0 = sub*128;
    double acc = 0;
    for (int k = k0; k < k0 + 128; ++k) acc += e1[(size_t)b*DD + k] * e2R[k];
    red[tid] = acc; __syncthreads();
    if (sub == 0){
      double pv = red[tid]+red[tid+1]+red[tid+2]+red[tid+3];
      double wv = 1.0 / (DELTA0 - pv);
      int j = a*64 + b;
      p[j] = pv; w[j] = wv; p32[j] = (float)pv; w32[j] = (float)wv;
    }
  }
  gsync(cnt, gen, mygen);   // G2

  // ---------- Phase 3: sums (redundant) + FUSED formula pivot-1 (E' diag) -> KsB ----------
  {
    double* sumsL = SH;          // 392
    double* red3  = SH + 392;    // 768
    double* invd  = SH + 1160;   // 64
    double* temp  = SH + 1224;   // 5*68 = 340
    int a = tid >> 2, sub = tid & 3;
    double r0 = 0, r1 = 0, r2 = 0;
    for (int b = sub*16; b < sub*16 + 16; ++b){
      double wv = w[a*64 + b], pv = p[a*64 + b];
      r0 += wv; r1 += wv*pv; r2 += wv*pv*pv;
    }
    red3[tid*3] = r0; red3[tid*3+1] = r1; red3[tid*3+2] = r2;
    __syncthreads();
    if (tid < 64){
      double t0 = 0, t1 = 0, t2 = 0;
      for (int s = 0; s < 4; ++s){
        t0 += red3[(tid*4+s)*3]; t1 += red3[(tid*4+s)*3+1]; t2 += red3[(tid*4+s)*3+2];
      }
      sumsL[200 + tid] = t0; sumsL[200 + 64 + tid] = t1; sumsL[200 + 128 + tid] = t2;
    }
    __syncthreads();
    int b2 = tid >> 2;
    double c0 = 0, c1 = 0, c2 = 0;
    for (int a2 = sub*16; a2 < sub*16 + 16; ++a2){
      double wv = w[a2*64 + b2], pv = p[a2*64 + b2];
      c0 += wv; c1 += wv*pv; c2 += wv*pv*pv;
    }
    __syncthreads();
    red3[tid*3] = c0; red3[tid*3+1] = c1; red3[tid*3+2] = c2;
    __syncthreads();
    if (tid < 64){
      double t0 = 0, t1 = 0, t2 = 0;
      for (int s = 0; s < 4; ++s){
        t0 += red3[(tid*4+s)*3]; t1 += red3[(tid*4+s)*3+1]; t2 += red3[(tid*4+s)*3+2];
      }
      sumsL[8 + tid] = t0; sumsL[8 + 64 + tid] = t1; sumsL[8 + 128 + tid] = t2;
    }
    __syncthreads();
    if (tid == 0){
      double t0 = 0, t1 = 0, t2 = 0;
      for (int a3 = 0; a3 < 64; ++a3){
        t0 += sumsL[200 + a3]; t1 += sumsL[200 + 64 + a3]; t2 += sumsL[200 + 128 + a3];
      }
      sumsL[0] = t0; sumsL[1] = t1; sumsL[2] = t2;
    }
    __syncthreads();
    // pivot 1: E' block is exactly diagonal; d_k = cs2[k] - 4*rho
    if (tid < 64) invd[tid] = 1.0 / (sumsL[8 + 128 + tid] - 4.0*RHO_);
    __syncthreads();
    int ncols = (wg < 2) ? 5 : 4;
    for (int idx = tid; idx < ncols*64; idx += 256){
      int cidx = idx >> 6, k = idx & 63;
      int c = wg + 64*cidx;
      double tv;
      if (c < 64) tv = (k == c) ? invd[k] : 0.0;
      else        tv = ksval(k, c, p, w, sumsL) * invd[k];
      temp[cidx*68 + k] = tv;
    }
    __syncthreads();
    for (int r = tid; r < NS; r += 256){
      if (r < 64){
        for (int cidx = 0; cidx < ncols; ++cidx)
          KsB[(size_t)r*NSP + wg + 64*cidx] = temp[cidx*68 + r];
      } else {
        double acc[5];
        for (int cidx = 0; cidx < ncols; ++cidx){
          int c = wg + 64*cidx;
          acc[cidx] = (c < 64) ? 0.0 : ksval(r, c, p, w, sumsL);
        }
        for (int k = 0; k < 64; ++k){
          double s = ksval(r, k, p, w, sumsL);
          for (int cidx = 0; cidx < ncols; ++cidx) acc[cidx] -= s * temp[cidx*68 + k];
        }
        for (int cidx = 0; cidx < ncols; ++cidx)
          KsB[(size_t)r*NSP + wg + 64*cidx] = acc[cidx];
      }
    }
  }
  gsync(cnt, gen, mygen);   // G3

  // ---------- Phases 4-6: remaining GJ pivots, one gsync each, ping-pong ----------
  {
    double* M    = SH;           // up to 66*67 = 4422
    double* temp = SH + 4422;    // 5*68 = 340
    double* rcv  = SH + 4762;    // 132
    pivot_phase(KsB, KsA, nullptr, 64,  66, wg, tid, M, temp, rcv);
    gsync(cnt, gen, mygen);   // G4
    pivot_phase(KsA, KsB, nullptr, 130, 64, wg, tid, M, temp, rcv);
    gsync(cnt, gen, mygen);   // G5
    pivot_phase(KsB, nullptr, N32, 194, 64, wg, tid, M, temp, rcv);
  }
}

// =================== K2: persistent single-WG ADMM + softmax (fp32 LDS) ===================
// s1/s2 admm ordering: [0..63]=cs(pt) E', [64..127]=rs(pt) F', [128..191]=cs(t) E,
// [192..255]=rs(t) F, row256=g'(tot pt), row257=g(tot t)
__global__ __launch_bounds__(1024, 4) void k_admm(const float* __restrict__ N32,
                                                  const float* __restrict__ p32,
                                                  const float* __restrict__ w32,
                                                  float* __restrict__ out){
  __shared__ float2 tb[64][66];       // (t, p*t) staging; reused for x^T at end
  __shared__ float2 csTP[64][18];     // col-sum partials (t, p*t) per (b, wave)
  __shared__ float  csXl[64][18];     // col-sum partials of x per (b, wave)
  __shared__ __align__(16) float s1f[264];
  __shared__ float s1g2[2];           // [0]=tot(pt), [1]=tot(t)
  __shared__ float s2g[2];            // [0]=a_pg (row 256), [1]=a_g (row 257)
  __shared__ __align__(16) float s2p[4][264];   // matvec partials (fp32)
  __shared__ float2 pairB[64];        // (sbE, sbPE) per b
  __shared__ float2 pairR[64];        // (a_g + sF, a_pg + sPF) per a

  const int tid  = threadIdx.x;
  const int lane = tid & 63;          // b
  const int wvid = tid >> 6;          // wave -> rows a = 4*wvid..+3
  const int g    = tid >> 8;          // matvec jj-group
  const int c    = tid & 255;         // matvec column

  // ---- register cache of N column c ----
  float nc[64];
#pragma unroll
  for (int k = 0; k < 64; ++k) nc[k] = N32[(64*g + k)*NSP + c];
  const float ncg0 = N32[256*NSP + c];
  const float ncg1 = N32[257*NSP + c];

  // tot-row cache for waves 4/5
  float nr0 = 0.f, nr1 = 0.f, nr2 = 0.f, nr3 = 0.f, nrt0 = 0.f, nrt1 = 0.f;
  if (wvid == 4 || wvid == 5){
    int r = 252 + wvid;   // 256 or 257
    nr0 = N32[r*NSP + lane];       nr1 = N32[r*NSP + lane + 64];
    nr2 = N32[r*NSP + lane + 128]; nr3 = N32[r*NSP + lane + 192];
    nrt0 = N32[r*NSP + 256];       nrt1 = N32[r*NSP + 257];
  }

  // ---- state: fp32, f64 dual integrators ----
  float pr[4], wr[4], xr[4], vr[4], tq[4];
  double y2a[4], y2b = 0.0;
#pragma unroll
  for (int q = 0; q < 4; ++q){
    int j = (wvid*4 + q)*64 + lane;
    pr[q] = p32[j]; wr[q] = w32[j];
    xr[q] = 0.f; vr[q] = 0.f; tq[q] = 0.f; y2a[q] = 0.0;
  }
  __syncthreads();

  const int rid = tid >> 4, g16 = tid & 15;

  for (int it = 0; it < NITER; ++it){
    // ========== S1: y2b fold, t = w*rhs (fp32), stage (t,pt), col partials ==========
    if (it){
      float ybs = 0.f;
#pragma unroll
      for (int s = 0; s < 8; ++s){
        float2 v2 = *(const float2*)&csXl[lane][2*s];
        ybs += v2.x + v2.y;
      }
      y2b += RHO_ * ((double)ybs - 1.0);
    }
    float base = (float)(2.0*RHO_ - y2b);
    float clt = 0.f, clp = 0.f;
#pragma unroll
    for (int q = 0; q < 4; ++q){
      float ya = (float)y2a[q];
      float rhs = 1e-3f*xr[q] + pr[q] + 100.f*fabsf(vr[q]) + base - ya;
      float t = wr[q]*rhs;
      float pt = pr[q]*t;
      tq[q] = t;
      tb[wvid*4 + q][lane] = make_float2(t, pt);
      clt += t; clp += pt;
    }
    csTP[lane][(wvid + lane) & 15] = make_float2(clt, clp);
    __syncthreads();  // B1

    // ========== S2: build s1 + totals ==========
    {
      const float4 r0 = *(const float4*)&tb[rid][4*g16];
      const float4 r1 = *(const float4*)&tb[rid][4*g16 + 2];
      float st = (r0.x + r0.z) + (r1.x + r1.z);
      float sp = (r0.y + r0.w) + (r1.y + r1.w);
      st = sum16(st); sp = sum16(sp);
      if (g16 == (rid & 15)){ s1f[192 + rid] = st; s1f[64 + rid] = sp; }
      if (wvid == 0){
        float ct = 0.f, cp = 0.f;
#pragma unroll
        for (int s = 0; s < 8; ++s){
          float4 v4 = *(const float4*)&csTP[lane][2*s];
          ct += v4.x + v4.z; cp += v4.y + v4.w;
        }
        s1f[128 + lane] = ct; s1f[lane] = cp;
        float tt = wsum64f(ct);
        float tp = wsum64f(cp);
        if (lane == 0){ s1g2[1] = tt; s1g2[0] = tp; }
      }
    }
    __syncthreads();  // B2

    // ========== S3: matvec s2p[g][c] = N[64g..64g+63][c] . s1 (fp32) ==========
    {
      float accA = 0.f, accB = 0.f;
      const float4* s4 = (const float4*)&s1f[64*g];
#pragma unroll
      for (int k2 = 0; k2 < 16; ++k2){
        float4 sv = s4[k2];
        accA += nc[4*k2]*sv.x + nc[4*k2+1]*sv.y;
        accB += nc[4*k2+2]*sv.z + nc[4*k2+3]*sv.w;
      }
      float acc = accA + accB;
      if (g == 0) acc += ncg0*s1g2[0] + ncg1*s1g2[1];
      s2p[g][c] = acc;
      if (wvid == 4 || wvid == 5){
        float a32 = nr0*s1f[lane] + nr1*s1f[lane+64]
                  + nr2*s1f[lane+128] + nr3*s1f[lane+192];
        a32 = wsum64f(a32);
        if (lane == 0) s2g[wvid - 4] = a32 + nrt0*s1g2[0] + nrt1*s1g2[1];
      }
    }
    __syncthreads();  // B3

    // ========== S4a: fold into packed pairs (2 waves) ==========
    if (tid < 64){
      int b = tid;
      float sbE  = (s2p[0][128+b] + s2p[1][128+b]) + (s2p[2][128+b] + s2p[3][128+b]);
      float sbPE = (s2p[0][b] + s2p[1][b]) + (s2p[2][b] + s2p[3][b]);
      pairB[b] = make_float2(sbE, sbPE);
    } else if (tid < 128){
      int a = tid - 64;
      float sF  = (s2p[0][192+a] + s2p[1][192+a]) + (s2p[2][192+a] + s2p[3][192+a]);
      float sPF = (s2p[0][64+a] + s2p[1][64+a]) + (s2p[2][64+a] + s2p[3][64+a]);
      pairR[a] = make_float2(s2g[1] + sF, s2g[0] + sPF);
    }
    __syncthreads();  // B4

    // ========== S4b: x update, v update, y2a, x col partials ==========
    {
      float2 pb = pairB[lane];
      float clx = 0.f;
#pragma unroll
      for (int q = 0; q < 4; ++q){
        int arow = wvid*4 + q;
        float2 prw = pairR[arow];
        float corr = prw.x + pb.x + pr[q]*(prw.y + pb.y);
        float xn = tq[q] - wr[q]*corr;
        vr[q] = xn + fminf(vr[q], 0.f);
        xr[q] = xn;
        float rsx = wsum64f(xn);
        y2a[q] += RHO_*((double)rsx - 1.0);
        clx += xn;
        if (it == NITER-1) ((float*)tb)[lane*68 + arow] = xn;   // x^T for epilogue
      }
      csXl[lane][(wvid + lane) & 15] = clx;
    }
    __syncthreads();  // B5
  }

  // ========== epilogue: clip + softmax(ALPHA*s, axis=-1) ==========
  const float* xb = (const float*)tb;
#pragma unroll
  for (int q = 0; q < 4; ++q){
    int i = wvid*4 + q;                 // n1 row index
    float val = xb[i*68 + lane];        // x[a=lane][b=i]
    val = fminf(fmaxf(val, 0.f), 1.f);
    float mx = wmax64f(val);
    float e = expf(200.f*(val - mx));
    float sm = wsum64f(e);
    out[i*64 + lane] = e / sm;
  }
}

extern "C" void kernel_launch(void* const* d_in, const int* in_sizes, int n_in,
                              void* d_out, int out_size, void* d_ws, size_t ws_size,
                              hipStream_t stream){
  (void)in_sizes; (void)n_in; (void)out_size; (void)ws_size;
  const float* ft  = (const float*)d_in[0];
  const float* fd  = (const float*)d_in[1];
  const float* iou = (const float*)d_in[2];
  const float* Wm  = (const float*)d_in[3];
  const float* bb  = (const float*)d_in[4];
  char* ws = (char*)d_ws;

  hipMemsetAsync(ws + OFF_BAR, 0, 512, stream);
  hipLaunchKernelGGL(k_prep, dim3(NWG), dim3(256), 0, stream, ft, fd, iou, Wm, bb, ws);

  const float* N32 = (const float*)(ws + OFF_N32);
  const float* p32 = (const float*)(ws + OFF_P32);
  const float* w32 = (const float*)(ws + OFF_W32);
  hipLaunchKernelGGL(k_admm, dim3(1), dim3(1024), 0, stream, N32, p32, w32, (float*)d_out);
}